// Round 5
// baseline (5136.471 us; speedup 1.0000x reference)
//
#include <hip/hip_runtime.h>
#include <hip/hip_bf16.h>
#include <math.h>

#define B_   4
#define CIN  64
#define P_   1728
#define N_   1729
#define C_   256
#define NH_  8
#define HD_  32
#define M_   (B_*N_)   // 6916 rows

// ---------------------------------------------------------------------------
// Patch embed. One thread per (b, n, c); flat idx == t's flat layout.
// t[b,0,c] = cls[c];  t[b,1+p,c] = sum_ci x[b,ci,p]*Wpe[ci,c] + bpe[c]
// ---------------------------------------------------------------------------
__global__ __launch_bounds__(256) void embed2(
    const float* __restrict__ x, const float* __restrict__ Wpe,
    const float* __restrict__ bpe, const float* __restrict__ cls,
    float* __restrict__ t)
{
    int idx = blockIdx.x*256 + threadIdx.x;        // [0, B*N*C)
    int c   = idx & 255;
    int n   = (idx >> 8) % N_;
    int b   = idx / (N_*256);
    if (n == 0) { t[idx] = cls[c]; return; }
    int p = n - 1;
    float acc = bpe[c];
    for (int ci = 0; ci < CIN; ++ci)
        acc += x[(size_t)(b*CIN + ci)*P_ + p] * Wpe[ci*C_ + c];
    t[idx] = acc;
}

// ---------------------------------------------------------------------------
// LayerNorm over C=256, LDS tree reduction. One block per row.
// Optionally writes cls rows (n==0) to out_cls (fp32, final norm only).
// ---------------------------------------------------------------------------
__global__ __launch_bounds__(256) void ln2(
    const float* __restrict__ in, float* __restrict__ out,
    const float* __restrict__ g, const float* __restrict__ bb,
    float* __restrict__ cls_out)
{
    int row = blockIdx.x;
    int c   = threadIdx.x;
    __shared__ float red[256];
    float v = in[(size_t)row*C_ + c];

    red[c] = v; __syncthreads();
    for (int off = 128; off >= 1; off >>= 1) {
        if (c < off) red[c] += red[c+off];
        __syncthreads();
    }
    float mean = red[0] * (1.0f/C_);
    __syncthreads();

    float d = v - mean;
    red[c] = d*d; __syncthreads();
    for (int off = 128; off >= 1; off >>= 1) {
        if (c < off) red[c] += red[c+off];
        __syncthreads();
    }
    float var  = red[0] * (1.0f/C_);
    float rstd = rsqrtf(var + 1e-5f);
    float val  = d * rstd * g[c] + bb[c];
    out[(size_t)row*C_ + c] = val;
    if (cls_out && (row % N_) == 0)
        cls_out[(row / N_)*C_ + c] = val;
}

// ---------------------------------------------------------------------------
// GEMM: out[M,NC] (+)= A[M,256] @ W[256,NC] (+bias)(gelu). One row per block.
// ---------------------------------------------------------------------------
template<int NC, bool ADD, bool GELU>
__global__ __launch_bounds__(256) void gemm2(
    const float* __restrict__ A, const float* __restrict__ W,
    const float* __restrict__ bias, float* __restrict__ out)
{
    int r   = blockIdx.x;
    int col = blockIdx.y*256 + threadIdx.x;
    const float* arow = A + (size_t)r*C_;
    float acc = bias ? bias[col] : 0.0f;
    for (int k = 0; k < C_; ++k)
        acc += arow[k] * W[(size_t)k*NC + col];
    if (GELU) acc = 0.5f * acc * (1.0f + erff(acc * 0.70710678118654752f));
    size_t oi = (size_t)r*NC + col;
    if (ADD) out[oi] += acc; else out[oi] = acc;
}

// ---------------------------------------------------------------------------
// Attention, two-pass softmax, one block per (query n, head h, batch b).
// qkv row layout: [q(256) | k(256) | v(256)]; head h at +h*32 within each.
// ---------------------------------------------------------------------------
__global__ __launch_bounds__(256) void attn2(
    const float* __restrict__ qkv, float* __restrict__ o)
{
    int n = blockIdx.x, h = blockIdx.y, b = blockIdx.z;
    int tid = threadIdx.x;
    __shared__ float qs[HD_];
    __shared__ float sc[N_];
    __shared__ float red[256];

    const float* qrow = qkv + ((size_t)(b*N_ + n))*768 + h*HD_;
    if (tid < HD_) qs[tid] = qrow[tid] * 0.17677669529663687f;  // 1/sqrt(32)
    __syncthreads();

    for (int j = tid; j < N_; j += 256) {
        const float* krow = qkv + ((size_t)(b*N_ + j))*768 + 256 + h*HD_;
        float s = 0.0f;
        for (int d = 0; d < HD_; ++d) s += qs[d] * krow[d];
        sc[j] = s;
    }
    __syncthreads();

    float mx = -1e30f;
    for (int j = tid; j < N_; j += 256) mx = fmaxf(mx, sc[j]);
    red[tid] = mx; __syncthreads();
    for (int off = 128; off >= 1; off >>= 1) {
        if (tid < off) red[tid] = fmaxf(red[tid], red[tid+off]);
        __syncthreads();
    }
    mx = red[0];
    __syncthreads();

    float ls = 0.0f;
    for (int j = tid; j < N_; j += 256) {
        float p = expf(sc[j] - mx);
        sc[j] = p;
        ls += p;
    }
    red[tid] = ls; __syncthreads();
    for (int off = 128; off >= 1; off >>= 1) {
        if (tid < off) red[tid] += red[tid+off];
        __syncthreads();
    }
    float inv = 1.0f / red[0];

    int d = tid & 31, g = tid >> 5;
    float acc = 0.0f;
    for (int j = g; j < N_; j += 8) {
        const float* vrow = qkv + ((size_t)(b*N_ + j))*768 + 512 + h*HD_;
        acc += sc[j] * vrow[d];
    }
    __syncthreads();
    red[tid] = acc; __syncthreads();
    if (tid < HD_) {
        float s = red[tid] + red[tid+32] + red[tid+64] + red[tid+96]
                + red[tid+128] + red[tid+160] + red[tid+192] + red[tid+224];
        o[((size_t)(b*N_ + n))*C_ + h*HD_ + tid] = s * inv;
    }
}

// ---------------------------------------------------------------------------
// feat: out_feat[(b*256+c)*1728 + p] = y[(b*1729 + 1 + p)*256 + c]  (fp32)
// ---------------------------------------------------------------------------
__global__ __launch_bounds__(256) void feat2(
    const float* __restrict__ y, float* __restrict__ outf)
{
    int idx  = blockIdx.x*256 + threadIdx.x;   // [0, B*C*P)
    int p    = idx % P_;
    int rest = idx / P_;
    int c    = rest % C_;
    int b    = rest / C_;
    outf[idx] = y[((size_t)(b*N_) + 1 + p)*C_ + c];
}

// ---------------------------------------------------------------------------
extern "C" void kernel_launch(void* const* d_in, const int* in_sizes, int n_in,
                              void* d_out, int out_size, void* d_ws, size_t ws_size,
                              hipStream_t stream)
{
    const float* x        = (const float*)d_in[0];
    const float* W_pe     = (const float*)d_in[1];
    const float* b_pe     = (const float*)d_in[2];
    const float* cls_tok  = (const float*)d_in[3];
    const float* ln1_g    = (const float*)d_in[4];
    const float* ln1_b    = (const float*)d_in[5];
    const float* Wqkv     = (const float*)d_in[6];
    const float* Wproj    = (const float*)d_in[7];
    const float* bproj    = (const float*)d_in[8];
    const float* ln2_g    = (const float*)d_in[9];
    const float* ln2_b    = (const float*)d_in[10];
    const float* W1       = (const float*)d_in[11];
    const float* b1       = (const float*)d_in[12];
    const float* W2       = (const float*)d_in[13];
    const float* b2       = (const float*)d_in[14];
    const float* normf_g  = (const float*)d_in[15];
    const float* normf_b  = (const float*)d_in[16];

    float* ws   = (float*)d_ws;
    float* t    = ws;                       // M*256 fp32
    float* y    = ws + (size_t)M_*C_;       // M*256 fp32
    float* qkv  = ws + (size_t)2*M_*C_;     // M*768 fp32

    float* out_cls  = (float*)d_out;        // 4*256 fp32
    float* out_feat = out_cls + B_*C_;      // 4*256*1728 fp32

    embed2<<<(B_*N_*C_)/256, 256, 0, stream>>>(x, W_pe, b_pe, cls_tok, t);

    for (int i = 0; i < 2; ++i) {
        ln2<<<M_, 256, 0, stream>>>(t, y, ln1_g + i*C_, ln1_b + i*C_, nullptr);
        gemm2<768,false,false><<<dim3(M_,3), 256, 0, stream>>>(
            y, Wqkv + (size_t)i*C_*768, nullptr, qkv);
        attn2<<<dim3(N_, NH_, B_), 256, 0, stream>>>(qkv, y);
        gemm2<256,true,false><<<dim3(M_,1), 256, 0, stream>>>(
            y, Wproj + (size_t)i*C_*C_, bproj + i*C_, t);
        ln2<<<M_, 256, 0, stream>>>(t, y, ln2_g + i*C_, ln2_b + i*C_, nullptr);
        gemm2<256,false,true><<<dim3(M_,1), 256, 0, stream>>>(
            y, W1 + (size_t)i*C_*C_, b1 + i*C_, qkv);
        gemm2<256,true,false><<<dim3(M_,1), 256, 0, stream>>>(
            qkv, W2 + (size_t)i*C_*C_, b2 + i*C_, t);
    }

    ln2<<<M_, 256, 0, stream>>>(t, y, normf_g, normf_b, out_cls);
    feat2<<<(B_*C_*P_)/256, 256, 0, stream>>>(y, out_feat);
}

// Round 6
// 1506.417 us; speedup vs baseline: 3.4097x; 3.4097x over previous
//
#include <hip/hip_runtime.h>
#include <hip/hip_bf16.h>
#include <math.h>

#define B_   4
#define CIN  64
#define P_   1728
#define N_   1729
#define C_   256
#define NH_  8
#define HD_  32
#define M_   (B_*N_)   // 6916 rows

// ---------------------------------------------------------------------------
// Patch embed. One thread per (b, n, c).
// ---------------------------------------------------------------------------
__global__ __launch_bounds__(256) void embed2(
    const float* __restrict__ x, const float* __restrict__ Wpe,
    const float* __restrict__ bpe, const float* __restrict__ cls,
    float* __restrict__ t)
{
    int idx = blockIdx.x*256 + threadIdx.x;        // [0, B*N*C)
    int c   = idx & 255;
    int n   = (idx >> 8) % N_;
    int b   = idx / (N_*256);
    if (n == 0) { t[idx] = cls[c]; return; }
    int p = n - 1;
    float acc = bpe[c];
    for (int ci = 0; ci < CIN; ++ci)
        acc += x[(size_t)(b*CIN + ci)*P_ + p] * Wpe[ci*C_ + c];
    t[idx] = acc;
}

// ---------------------------------------------------------------------------
// LayerNorm over C=256, LDS tree reduction. One block per row.
// ---------------------------------------------------------------------------
__global__ __launch_bounds__(256) void ln2(
    const float* __restrict__ in, float* __restrict__ out,
    const float* __restrict__ g, const float* __restrict__ bb,
    float* __restrict__ cls_out)
{
    int row = blockIdx.x;
    int c   = threadIdx.x;
    __shared__ float red[256];
    float v = in[(size_t)row*C_ + c];

    red[c] = v; __syncthreads();
    for (int off = 128; off >= 1; off >>= 1) {
        if (c < off) red[c] += red[c+off];
        __syncthreads();
    }
    float mean = red[0] * (1.0f/C_);
    __syncthreads();

    float d = v - mean;
    red[c] = d*d; __syncthreads();
    for (int off = 128; off >= 1; off >>= 1) {
        if (c < off) red[c] += red[c+off];
        __syncthreads();
    }
    float var  = red[0] * (1.0f/C_);
    float rstd = rsqrtf(var + 1e-5f);
    float val  = d * rstd * g[c] + bb[c];
    out[(size_t)row*C_ + c] = val;
    if (cls_out && (row % N_) == 0)
        cls_out[(row / N_)*C_ + c] = val;
}

// ---------------------------------------------------------------------------
// GEMM: out[M,NC] (+)= A[M,256] @ W[256,NC] (+bias)(gelu). One row per block.
// ---------------------------------------------------------------------------
template<int NC, bool ADD, bool GELU>
__global__ __launch_bounds__(256) void gemm2(
    const float* __restrict__ A, const float* __restrict__ W,
    const float* __restrict__ bias, float* __restrict__ out)
{
    int r   = blockIdx.x;
    int col = blockIdx.y*256 + threadIdx.x;
    const float* arow = A + (size_t)r*C_;
    float acc = bias ? bias[col] : 0.0f;
    for (int k = 0; k < C_; ++k)
        acc += arow[k] * W[(size_t)k*NC + col];
    if (GELU) acc = 0.5f * acc * (1.0f + erff(acc * 0.70710678118654752f));
    size_t oi = (size_t)r*NC + col;
    if (ADD) out[oi] += acc; else out[oi] = acc;
}

// ---------------------------------------------------------------------------
// attn3: tiled flash-style attention, fp32.
// Block = (q-tile of 64, head, batch). 256 threads.
// Thread: q2 = tid&31 owns queries {q0+q2, q0+q2+32}; grp = tid>>5 owns
// keys grp*8..grp*8+7 of each 64-key tile. Online softmax; per-grp partial
// O/l combined in LDS at the end (all grps share identical m sequence).
// ---------------------------------------------------------------------------
#define TQ 64
#define TK 64
#define KPAD 36   // LDS row stride (floats): breaks pow-2 bank pattern, keeps 16B align

__global__ __launch_bounds__(256, 2) void attn3(
    const float* __restrict__ qkv, float* __restrict__ o)
{
    int q0 = blockIdx.x * TQ;
    int h  = blockIdx.y, b = blockIdx.z;
    int q2  = threadIdx.x & 31;
    int grp = threadIdx.x >> 5;

    __shared__ float lds_k[TK][KPAD];
    __shared__ float lds_v[TK][KPAD];
    __shared__ float redm[8][64];
    __shared__ float redl[8][64];
    __shared__ float lds_o[64][32];

    const float scale = 0.17677669529663687f;   // 1/sqrt(32)

    int qa = q0 + q2, qb = q0 + q2 + 32;
    float qra[32], qrb[32];
    {
        int ra = (qa < N_) ? qa : 0;
        int rb = (qb < N_) ? qb : 0;
        const float* pa = qkv + ((size_t)(b*N_ + ra))*768 + h*HD_;
        const float* pb = qkv + ((size_t)(b*N_ + rb))*768 + h*HD_;
        #pragma unroll
        for (int d = 0; d < 32; ++d) { qra[d] = pa[d]*scale; qrb[d] = pb[d]*scale; }
    }

    float ma = -1e30f, mb = -1e30f, la = 0.f, lb = 0.f;
    float oa[32], ob[32];
    #pragma unroll
    for (int d = 0; d < 32; ++d) { oa[d] = 0.f; ob[d] = 0.f; }

    const int ntiles = (N_ + TK - 1) / TK;   // 28
    for (int t = 0; t < ntiles; ++t) {
        int k0 = t * TK;
        __syncthreads();   // protect lds_k/lds_v from previous iteration's readers
        {
            int row = threadIdx.x >> 2;
            int dd  = (threadIdx.x & 3) * 8;
            int src = k0 + row; if (src >= N_) src = 0;
            const float* kp = qkv + ((size_t)(b*N_ + src))*768 + 256 + h*HD_ + dd;
            float4 k1 = *(const float4*)kp,     k2 = *(const float4*)(kp+4);
            float4 v1 = *(const float4*)(kp+256), v2 = *(const float4*)(kp+260);
            *(float4*)&lds_k[row][dd]   = k1;
            *(float4*)&lds_k[row][dd+4] = k2;
            *(float4*)&lds_v[row][dd]   = v1;
            *(float4*)&lds_v[row][dd+4] = v2;
        }
        __syncthreads();

        // scores: 8 keys x 2 queries, K row register-cached
        float sa[8], sb[8];
        #pragma unroll
        for (int kk = 0; kk < 8; ++kk) {
            int krow = grp*8 + kk;
            float kreg[32];
            #pragma unroll
            for (int d4 = 0; d4 < 8; ++d4)
                *(float4*)&kreg[d4*4] = *(const float4*)&lds_k[krow][d4*4];
            float aA = 0.f, aB = 0.f;
            #pragma unroll
            for (int d = 0; d < 32; ++d) { aA += qra[d]*kreg[d]; aB += qrb[d]*kreg[d]; }
            bool valid = (k0 + krow) < N_;
            sa[kk] = valid ? aA : -1e30f;
            sb[kk] = valid ? aB : -1e30f;
        }
        float mta = sa[0], mtb = sb[0];
        #pragma unroll
        for (int kk = 1; kk < 8; ++kk) { mta = fmaxf(mta, sa[kk]); mtb = fmaxf(mtb, sb[kk]); }
        redm[grp][q2]    = mta;
        redm[grp][q2+32] = mtb;
        __syncthreads();
        float Ma = redm[0][q2], Mb = redm[0][q2+32];
        #pragma unroll
        for (int g = 1; g < 8; ++g) { Ma = fmaxf(Ma, redm[g][q2]); Mb = fmaxf(Mb, redm[g][q2+32]); }

        float mna = fmaxf(ma, Ma), mnb = fmaxf(mb, Mb);
        float alA = __expf(ma - mna), alB = __expf(mb - mnb);
        float pA[8], pB[8]; float sAs = 0.f, sBs = 0.f;
        #pragma unroll
        for (int kk = 0; kk < 8; ++kk) {
            pA[kk] = __expf(sa[kk] - mna); sAs += pA[kk];
            pB[kk] = __expf(sb[kk] - mnb); sBs += pB[kk];
        }
        la = la*alA + sAs; lb = lb*alB + sBs;
        ma = mna; mb = mnb;
        #pragma unroll
        for (int d = 0; d < 32; ++d) { oa[d] *= alA; ob[d] *= alB; }
        #pragma unroll
        for (int kk = 0; kk < 8; ++kk) {
            int krow = grp*8 + kk;
            float vreg[32];
            #pragma unroll
            for (int d4 = 0; d4 < 8; ++d4)
                *(float4*)&vreg[d4*4] = *(const float4*)&lds_v[krow][d4*4];
            float pa1 = pA[kk], pb1 = pB[kk];
            #pragma unroll
            for (int d = 0; d < 32; ++d) { oa[d] += pa1*vreg[d]; ob[d] += pb1*vreg[d]; }
        }
    }

    // combine partial O/l across the 8 key-groups
    redl[grp][q2]    = la;
    redl[grp][q2+32] = lb;
    for (int g = 0; g < 8; ++g) {
        __syncthreads();
        if (grp == g) {
            if (g == 0) {
                #pragma unroll
                for (int d = 0; d < 32; ++d) { lds_o[q2][d] = oa[d]; lds_o[q2+32][d] = ob[d]; }
            } else {
                #pragma unroll
                for (int d = 0; d < 32; ++d) { lds_o[q2][d] += oa[d]; lds_o[q2+32][d] += ob[d]; }
            }
        }
    }
    __syncthreads();

    for (int e = threadIdx.x; e < TQ*32; e += 256) {
        int q = e >> 5, d = e & 31;
        if (q0 + q >= N_) continue;
        float lt = 0.f;
        #pragma unroll
        for (int g = 0; g < 8; ++g) lt += redl[g][q];
        o[((size_t)(b*N_ + q0 + q))*C_ + h*HD_ + d] = lds_o[q][d] / lt;
    }
}

// ---------------------------------------------------------------------------
// feat: out_feat[(b*256+c)*1728 + p] = y[(b*1729 + 1 + p)*256 + c]  (fp32)
// ---------------------------------------------------------------------------
__global__ __launch_bounds__(256) void feat2(
    const float* __restrict__ y, float* __restrict__ outf)
{
    int idx  = blockIdx.x*256 + threadIdx.x;   // [0, B*C*P)
    int p    = idx % P_;
    int rest = idx / P_;
    int c    = rest % C_;
    int b    = rest / C_;
    outf[idx] = y[((size_t)(b*N_) + 1 + p)*C_ + c];
}

// ---------------------------------------------------------------------------
extern "C" void kernel_launch(void* const* d_in, const int* in_sizes, int n_in,
                              void* d_out, int out_size, void* d_ws, size_t ws_size,
                              hipStream_t stream)
{
    const float* x        = (const float*)d_in[0];
    const float* W_pe     = (const float*)d_in[1];
    const float* b_pe     = (const float*)d_in[2];
    const float* cls_tok  = (const float*)d_in[3];
    const float* ln1_g    = (const float*)d_in[4];
    const float* ln1_b    = (const float*)d_in[5];
    const float* Wqkv     = (const float*)d_in[6];
    const float* Wproj    = (const float*)d_in[7];
    const float* bproj    = (const float*)d_in[8];
    const float* ln2_g    = (const float*)d_in[9];
    const float* ln2_b    = (const float*)d_in[10];
    const float* W1       = (const float*)d_in[11];
    const float* b1       = (const float*)d_in[12];
    const float* W2       = (const float*)d_in[13];
    const float* b2       = (const float*)d_in[14];
    const float* normf_g  = (const float*)d_in[15];
    const float* normf_b  = (const float*)d_in[16];

    float* ws   = (float*)d_ws;
    float* t    = ws;                       // M*256 fp32
    float* y    = ws + (size_t)M_*C_;       // M*256 fp32
    float* qkv  = ws + (size_t)2*M_*C_;     // M*768 fp32

    float* out_cls  = (float*)d_out;        // 4*256 fp32
    float* out_feat = out_cls + B_*C_;      // 4*256*1728 fp32

    embed2<<<(B_*N_*C_)/256, 256, 0, stream>>>(x, W_pe, b_pe, cls_tok, t);

    for (int i = 0; i < 2; ++i) {
        ln2<<<M_, 256, 0, stream>>>(t, y, ln1_g + i*C_, ln1_b + i*C_, nullptr);
        gemm2<768,false,false><<<dim3(M_,3), 256, 0, stream>>>(
            y, Wqkv + (size_t)i*C_*768, nullptr, qkv);
        attn3<<<dim3((N_+TQ-1)/TQ, NH_, B_), 256, 0, stream>>>(qkv, y);
        gemm2<256,true,false><<<dim3(M_,1), 256, 0, stream>>>(
            y, Wproj + (size_t)i*C_*C_, bproj + i*C_, t);
        ln2<<<M_, 256, 0, stream>>>(t, y, ln2_g + i*C_, ln2_b + i*C_, nullptr);
        gemm2<256,false,true><<<dim3(M_,1), 256, 0, stream>>>(
            y, W1 + (size_t)i*C_*C_, b1 + i*C_, qkv);
        gemm2<256,true,false><<<dim3(M_,1), 256, 0, stream>>>(
            qkv, W2 + (size_t)i*C_*C_, b2 + i*C_, t);
    }

    ln2<<<M_, 256, 0, stream>>>(t, y, normf_g, normf_b, out_cls);
    feat2<<<(B_*C_*P_)/256, 256, 0, stream>>>(y, out_feat);
}

// Round 7
// 1053.838 us; speedup vs baseline: 4.8741x; 1.4295x over previous
//
#include <hip/hip_runtime.h>
#include <hip/hip_bf16.h>
#include <math.h>

#define B_   4
#define CIN  64
#define P_   1728
#define N_   1729
#define C_   256
#define NH_  8
#define HD_  32
#define M_   (B_*N_)   // 6916 rows

typedef __bf16 bf16x8 __attribute__((ext_vector_type(8)));
typedef float  f32x4  __attribute__((ext_vector_type(4)));

// ---------------------------------------------------------------------------
// Patch embed. One thread per (b, n, c).
// ---------------------------------------------------------------------------
__global__ __launch_bounds__(256) void embed2(
    const float* __restrict__ x, const float* __restrict__ Wpe,
    const float* __restrict__ bpe, const float* __restrict__ cls,
    float* __restrict__ t)
{
    int idx = blockIdx.x*256 + threadIdx.x;        // [0, B*N*C)
    int c   = idx & 255;
    int n   = (idx >> 8) % N_;
    int b   = idx / (N_*256);
    if (n == 0) { t[idx] = cls[c]; return; }
    int p = n - 1;
    float acc = bpe[c];
    for (int ci = 0; ci < CIN; ++ci)
        acc += x[(size_t)(b*CIN + ci)*P_ + p] * Wpe[ci*C_ + c];
    t[idx] = acc;
}

// ---------------------------------------------------------------------------
// LayerNorm over C=256, LDS tree reduction. One block per row.
// ---------------------------------------------------------------------------
__global__ __launch_bounds__(256) void ln2(
    const float* __restrict__ in, float* __restrict__ out,
    const float* __restrict__ g, const float* __restrict__ bb,
    float* __restrict__ cls_out)
{
    int row = blockIdx.x;
    int c   = threadIdx.x;
    __shared__ float red[256];
    float v = in[(size_t)row*C_ + c];

    red[c] = v; __syncthreads();
    for (int off = 128; off >= 1; off >>= 1) {
        if (c < off) red[c] += red[c+off];
        __syncthreads();
    }
    float mean = red[0] * (1.0f/C_);
    __syncthreads();

    float d = v - mean;
    red[c] = d*d; __syncthreads();
    for (int off = 128; off >= 1; off >>= 1) {
        if (c < off) red[c] += red[c+off];
        __syncthreads();
    }
    float var  = red[0] * (1.0f/C_);
    float rstd = rsqrtf(var + 1e-5f);
    float val  = d * rstd * g[c] + bb[c];
    out[(size_t)row*C_ + c] = val;
    if (cls_out && (row % N_) == 0)
        cls_out[(row / N_)*C_ + c] = val;
}

// ---------------------------------------------------------------------------
// Weight prep: Wt[n][k] = bf16(W[k][n]).  grid = (NC/32, 256/32), 256 thr.
// LDS-tiled transpose; coalesced read and write.
// ---------------------------------------------------------------------------
__global__ __launch_bounds__(256) void wprep(
    const float* __restrict__ W, __bf16* __restrict__ Wt, int NC)
{
    __shared__ float tile[32][33];
    int n0 = blockIdx.x*32, k0 = blockIdx.y*32;
    int c = threadIdx.x & 31, r = threadIdx.x >> 5;   // r = 0..7
    for (int rr = r; rr < 32; rr += 8)
        tile[rr][c] = W[(size_t)(k0+rr)*NC + n0 + c];
    __syncthreads();
    for (int rr = r; rr < 32; rr += 8)
        Wt[(size_t)(n0+rr)*256 + k0 + c] = (__bf16)tile[c][rr];
}

// ---------------------------------------------------------------------------
// MFMA GEMM: out[M,NC] (+)= A[M,256] @ W[256,NC] (+bias)(gelu).
// A fp32 (row stride 256), W as prepped bf16 W^T[n][k]. 64x64 tile, BK=32.
// 4 waves; wave w computes rows [w*16, w*16+16) x 64 cols via 4 MFMAs/k-iter.
// Frag layouts (verified, guide §3): A/B [m|n=lane&15][k=quad*8+j],
// C/D row=quad*4+reg, col=lane&15.
// ---------------------------------------------------------------------------
template<int NC, bool ADD, bool GELU, bool BIAS>
__global__ __launch_bounds__(256) void gemm_mfma(
    const float* __restrict__ A, const __bf16* __restrict__ Wt,
    const float* __restrict__ bias, float* __restrict__ out)
{
    __shared__ __bf16 As[64][32];
    __shared__ __bf16 Bs[64][32];
    int r0 = blockIdx.x*64, c0 = blockIdx.y*64;
    int tid = threadIdx.x;
    int wv = tid >> 6, lane = tid & 63, quad = lane >> 4, mn = lane & 15;
    int sr = tid >> 2, sc = (tid & 3) * 8;   // staging: row 0..63, k-offset

    f32x4 acc[4];
    #pragma unroll
    for (int ct = 0; ct < 4; ++ct)
        #pragma unroll
        for (int rr = 0; rr < 4; ++rr) acc[ct][rr] = 0.f;

    for (int kc = 0; kc < 8; ++kc) {
        __syncthreads();
        {   // stage A (fp32 -> bf16)
            int gr = r0 + sr;
            float v[8];
            if (gr < M_) {
                float4 f1 = *(const float4*)&A[(size_t)gr*256 + kc*32 + sc];
                float4 f2 = *(const float4*)&A[(size_t)gr*256 + kc*32 + sc + 4];
                v[0]=f1.x; v[1]=f1.y; v[2]=f1.z; v[3]=f1.w;
                v[4]=f2.x; v[5]=f2.y; v[6]=f2.z; v[7]=f2.w;
            } else {
                #pragma unroll
                for (int i = 0; i < 8; ++i) v[i] = 0.f;
            }
            bf16x8 bv;
            #pragma unroll
            for (int i = 0; i < 8; ++i) bv[i] = (__bf16)v[i];
            *(bf16x8*)&As[sr][sc] = bv;
            // stage B (already bf16, W^T layout): 16B raw copy
            *(uint4*)&Bs[sr][sc] = *(const uint4*)&Wt[(size_t)(c0+sr)*256 + kc*32 + sc];
        }
        __syncthreads();

        bf16x8 a = *(const bf16x8*)&As[wv*16 + mn][quad*8];
        #pragma unroll
        for (int ct = 0; ct < 4; ++ct) {
            bf16x8 b = *(const bf16x8*)&Bs[ct*16 + mn][quad*8];
            acc[ct] = __builtin_amdgcn_mfma_f32_16x16x32_bf16(a, b, acc[ct], 0, 0, 0);
        }
    }

    #pragma unroll
    for (int ct = 0; ct < 4; ++ct) {
        int col = c0 + ct*16 + mn;
        #pragma unroll
        for (int rr = 0; rr < 4; ++rr) {
            int row = r0 + wv*16 + quad*4 + rr;
            if (row >= M_) continue;
            float val = acc[ct][rr];
            if (BIAS) val += bias[col];
            if (GELU) val = 0.5f*val*(1.f + erff(val*0.70710678118654752f));
            size_t oi = (size_t)row*NC + col;
            if (ADD) out[oi] += val; else out[oi] = val;
        }
    }
}

// ---------------------------------------------------------------------------
// attn4: flash-style fp32 attention, spill-free.
// Block = (q-tile 64, head, batch), 256 thr = 4 waves.
// q = tid&63 (one query/thread), grp = tid>>6 (wave) owns 16 keys/tile.
// Wave-uniform K/V rows -> LDS broadcast reads. Online softmax with shared
// per-tile max; per-group partial O/l combined via 33-padded LDS.
// ---------------------------------------------------------------------------
__global__ __launch_bounds__(256, 2) void attn4(
    const float* __restrict__ qkv, float* __restrict__ o)
{
    int q0 = blockIdx.x * 64;
    int h  = blockIdx.y, b = blockIdx.z;
    int tid = threadIdx.x;
    int q   = tid & 63;
    int grp = tid >> 6;

    __shared__ float lk[64][36], lv[64][36];
    __shared__ float redm[4][64], redl[4][64];
    __shared__ float part[4][64][33];

    const float scale = 0.17677669529663687f;   // 1/sqrt(32)

    float qr[32];
    {
        int qi = q0 + q; if (qi >= N_) qi = N_ - 1;
        const float* qp = qkv + ((size_t)(b*N_ + qi))*768 + h*HD_;
        #pragma unroll
        for (int d4 = 0; d4 < 8; ++d4) {
            float4 f = *(const float4*)(qp + d4*4);
            qr[d4*4+0] = f.x*scale; qr[d4*4+1] = f.y*scale;
            qr[d4*4+2] = f.z*scale; qr[d4*4+3] = f.w*scale;
        }
    }

    float m = -1e30f, l = 0.f;
    float oacc[32];
    #pragma unroll
    for (int d = 0; d < 32; ++d) oacc[d] = 0.f;

    const int ntiles = (N_ + 63) / 64;   // 28
    int sr = tid >> 2, sc = (tid & 3) * 8;
    for (int t = 0; t < ntiles; ++t) {
        int k0 = t * 64;
        __syncthreads();                          // B1: prev readers done
        {
            int src = k0 + sr; if (src >= N_) src = N_ - 1;
            const float* kp = qkv + ((size_t)(b*N_ + src))*768 + 256 + h*HD_ + sc;
            float4 k1 = *(const float4*)kp,       k2 = *(const float4*)(kp+4);
            float4 v1 = *(const float4*)(kp+256), v2 = *(const float4*)(kp+260);
            *(float4*)&lk[sr][sc]   = k1;  *(float4*)&lk[sr][sc+4] = k2;
            *(float4*)&lv[sr][sc]   = v1;  *(float4*)&lv[sr][sc+4] = v2;
        }
        __syncthreads();                          // B2

        float s[16];
        #pragma unroll
        for (int kk = 0; kk < 16; ++kk) {
            int krow = grp*16 + kk;               // wave-uniform
            float a = 0.f;
            #pragma unroll
            for (int d4 = 0; d4 < 8; ++d4) {
                float4 kv = *(const float4*)&lk[krow][d4*4];
                a += qr[d4*4+0]*kv.x + qr[d4*4+1]*kv.y
                   + qr[d4*4+2]*kv.z + qr[d4*4+3]*kv.w;
            }
            s[kk] = (k0 + krow < N_) ? a : -1e30f;
        }
        float mt = s[0];
        #pragma unroll
        for (int kk = 1; kk < 16; ++kk) mt = fmaxf(mt, s[kk]);
        redm[grp][q] = mt;
        __syncthreads();                          // B3
        float Mt = fmaxf(fmaxf(redm[0][q], redm[1][q]),
                         fmaxf(redm[2][q], redm[3][q]));

        float mn = fmaxf(m, Mt);
        float al = __expf(m - mn);
        float p[16], ps = 0.f;
        #pragma unroll
        for (int kk = 0; kk < 16; ++kk) { p[kk] = __expf(s[kk] - mn); ps += p[kk]; }
        l = l*al + ps;
        m = mn;
        #pragma unroll
        for (int d = 0; d < 32; ++d) oacc[d] *= al;
        #pragma unroll
        for (int kk = 0; kk < 16; ++kk) {
            int krow = grp*16 + kk;
            float pk = p[kk];
            #pragma unroll
            for (int d4 = 0; d4 < 8; ++d4) {
                float4 vv = *(const float4*)&lv[krow][d4*4];
                oacc[d4*4+0] += pk*vv.x; oacc[d4*4+1] += pk*vv.y;
                oacc[d4*4+2] += pk*vv.z; oacc[d4*4+3] += pk*vv.w;
            }
        }
    }

    redl[grp][q] = l;
    #pragma unroll
    for (int d = 0; d < 32; ++d) part[grp][q][d] = oacc[d];
    __syncthreads();

    int qo = tid & 63, d0 = (tid >> 6) * 8;
    if (q0 + qo < N_) {
        float lt = redl[0][qo] + redl[1][qo] + redl[2][qo] + redl[3][qo];
        float inv = 1.f / lt;
        #pragma unroll
        for (int dd = 0; dd < 8; ++dd) {
            int d = d0 + dd;
            float sm = part[0][qo][d] + part[1][qo][d]
                     + part[2][qo][d] + part[3][qo][d];
            o[((size_t)(b*N_ + q0 + qo))*C_ + h*HD_ + d] = sm * inv;
        }
    }
}

// ---------------------------------------------------------------------------
// feat: out_feat[(b*256+c)*1728 + p] = y[(b*1729 + 1 + p)*256 + c]  (fp32)
// ---------------------------------------------------------------------------
__global__ __launch_bounds__(256) void feat2(
    const float* __restrict__ y, float* __restrict__ outf)
{
    int idx  = blockIdx.x*256 + threadIdx.x;   // [0, B*C*P)
    int p    = idx % P_;
    int rest = idx / P_;
    int c    = rest % C_;
    int b    = rest / C_;
    outf[idx] = y[((size_t)(b*N_) + 1 + p)*C_ + c];
}

// ---------------------------------------------------------------------------
extern "C" void kernel_launch(void* const* d_in, const int* in_sizes, int n_in,
                              void* d_out, int out_size, void* d_ws, size_t ws_size,
                              hipStream_t stream)
{
    const float* x        = (const float*)d_in[0];
    const float* W_pe     = (const float*)d_in[1];
    const float* b_pe     = (const float*)d_in[2];
    const float* cls_tok  = (const float*)d_in[3];
    const float* ln1_g    = (const float*)d_in[4];
    const float* ln1_b    = (const float*)d_in[5];
    const float* Wqkv     = (const float*)d_in[6];
    const float* Wproj    = (const float*)d_in[7];
    const float* bproj    = (const float*)d_in[8];
    const float* ln2_g    = (const float*)d_in[9];
    const float* ln2_b    = (const float*)d_in[10];
    const float* W1       = (const float*)d_in[11];
    const float* b1       = (const float*)d_in[12];
    const float* W2       = (const float*)d_in[13];
    const float* b2       = (const float*)d_in[14];
    const float* normf_g  = (const float*)d_in[15];
    const float* normf_b  = (const float*)d_in[16];

    float* ws   = (float*)d_ws;
    float* t    = ws;                       // M*256 fp32
    float* y    = ws + (size_t)M_*C_;       // M*256 fp32
    float* qkv  = ws + (size_t)2*M_*C_;     // M*768 fp32 (also h-buffer)
    __bf16* wT  = (__bf16*)(ws + (size_t)5*M_*C_);   // prepped weights

    __bf16* qkvT = wT;                       // 2 x 768*256
    __bf16* projT = wT + 2*768*256;          // 2 x 256*256
    __bf16* w1T   = projT + 2*256*256;
    __bf16* w2T   = w1T   + 2*256*256;

    float* out_cls  = (float*)d_out;        // 4*256 fp32
    float* out_feat = out_cls + B_*C_;      // 4*256*1728 fp32

    // weight prep (every call; graph-safe)
    for (int i = 0; i < 2; ++i) {
        wprep<<<dim3(768/32, 8), 256, 0, stream>>>(Wqkv + (size_t)i*C_*768, qkvT + (size_t)i*768*256, 768);
        wprep<<<dim3(256/32, 8), 256, 0, stream>>>(Wproj + (size_t)i*C_*C_, projT + (size_t)i*256*256, 256);
        wprep<<<dim3(256/32, 8), 256, 0, stream>>>(W1 + (size_t)i*C_*C_, w1T + (size_t)i*256*256, 256);
        wprep<<<dim3(256/32, 8), 256, 0, stream>>>(W2 + (size_t)i*C_*C_, w2T + (size_t)i*256*256, 256);
    }

    embed2<<<(B_*N_*C_)/256, 256, 0, stream>>>(x, W_pe, b_pe, cls_tok, t);

    const int GRID_M = (M_ + 63) / 64;   // 109
    for (int i = 0; i < 2; ++i) {
        ln2<<<M_, 256, 0, stream>>>(t, y, ln1_g + i*C_, ln1_b + i*C_, nullptr);
        gemm_mfma<768,false,false,false><<<dim3(GRID_M, 12), 256, 0, stream>>>(
            y, qkvT + (size_t)i*768*256, nullptr, qkv);
        attn4<<<dim3((N_+63)/64, NH_, B_), 256, 0, stream>>>(qkv, y);
        gemm_mfma<256,true,false,true><<<dim3(GRID_M, 4), 256, 0, stream>>>(
            y, projT + (size_t)i*256*256, bproj + i*C_, t);
        ln2<<<M_, 256, 0, stream>>>(t, y, ln2_g + i*C_, ln2_b + i*C_, nullptr);
        gemm_mfma<256,false,true,true><<<dim3(GRID_M, 4), 256, 0, stream>>>(
            y, w1T + (size_t)i*256*256, b1 + i*C_, qkv);
        gemm_mfma<256,true,false,true><<<dim3(GRID_M, 4), 256, 0, stream>>>(
            qkv, w2T + (size_t)i*256*256, b2 + i*C_, t);
    }

    ln2<<<M_, 256, 0, stream>>>(t, y, normf_g, normf_b, out_cls);
    feat2<<<(B_*C_*P_)/256, 256, 0, stream>>>(y, out_feat);
}

// Round 8
// 468.409 us; speedup vs baseline: 10.9658x; 2.2498x over previous
//
#include <hip/hip_runtime.h>
#include <hip/hip_bf16.h>
#include <math.h>

#define B_   4
#define CIN  64
#define P_   1728
#define N_   1729
#define C_   256
#define NH_  8
#define HD_  32
#define M_   (B_*N_)   // 6916 rows
#define NPAD 1792      // 28 * 64

typedef __bf16 bf16x8 __attribute__((ext_vector_type(8)));
typedef float  f32x4  __attribute__((ext_vector_type(4)));

// ---------------------------------------------------------------------------
// Patch embed. One thread per (b, n, c).
// ---------------------------------------------------------------------------
__global__ __launch_bounds__(256) void embed2(
    const float* __restrict__ x, const float* __restrict__ Wpe,
    const float* __restrict__ bpe, const float* __restrict__ cls,
    float* __restrict__ t)
{
    int idx = blockIdx.x*256 + threadIdx.x;        // [0, B*N*C)
    int c   = idx & 255;
    int n   = (idx >> 8) % N_;
    int b   = idx / (N_*256);
    if (n == 0) { t[idx] = cls[c]; return; }
    int p = n - 1;
    float acc = bpe[c];
    for (int ci = 0; ci < CIN; ++ci)
        acc += x[(size_t)(b*CIN + ci)*P_ + p] * Wpe[ci*C_ + c];
    t[idx] = acc;
}

// ---------------------------------------------------------------------------
// LayerNorm over C=256, LDS tree reduction. One block per row.
// ---------------------------------------------------------------------------
__global__ __launch_bounds__(256) void ln2(
    const float* __restrict__ in, float* __restrict__ out,
    const float* __restrict__ g, const float* __restrict__ bb,
    float* __restrict__ cls_out)
{
    int row = blockIdx.x;
    int c   = threadIdx.x;
    __shared__ float red[256];
    float v = in[(size_t)row*C_ + c];

    red[c] = v; __syncthreads();
    for (int off = 128; off >= 1; off >>= 1) {
        if (c < off) red[c] += red[c+off];
        __syncthreads();
    }
    float mean = red[0] * (1.0f/C_);
    __syncthreads();

    float d = v - mean;
    red[c] = d*d; __syncthreads();
    for (int off = 128; off >= 1; off >>= 1) {
        if (c < off) red[c] += red[c+off];
        __syncthreads();
    }
    float var  = red[0] * (1.0f/C_);
    float rstd = rsqrtf(var + 1e-5f);
    float val  = d * rstd * g[c] + bb[c];
    out[(size_t)row*C_ + c] = val;
    if (cls_out && (row % N_) == 0)
        cls_out[(row / N_)*C_ + c] = val;
}

// ---------------------------------------------------------------------------
// Weight prep: Wt[n][k] = bf16(W[k][n]).
// ---------------------------------------------------------------------------
__global__ __launch_bounds__(256) void wprep(
    const float* __restrict__ W, __bf16* __restrict__ Wt, int NC)
{
    __shared__ float tile[32][33];
    int n0 = blockIdx.x*32, k0 = blockIdx.y*32;
    int c = threadIdx.x & 31, r = threadIdx.x >> 5;   // r = 0..7
    for (int rr = r; rr < 32; rr += 8)
        tile[rr][c] = W[(size_t)(k0+rr)*NC + n0 + c];
    __syncthreads();
    for (int rr = r; rr < 32; rr += 8)
        Wt[(size_t)(n0+rr)*256 + k0 + c] = (__bf16)tile[c][rr];
}

// ---------------------------------------------------------------------------
// MFMA GEMM: out[M,NC] (+)= A[M,256] @ W[256,NC] (+bias)(gelu). 64x64 tile.
// ---------------------------------------------------------------------------
template<int NC, bool ADD, bool GELU, bool BIAS>
__global__ __launch_bounds__(256) void gemm_mfma(
    const float* __restrict__ A, const __bf16* __restrict__ Wt,
    const float* __restrict__ bias, float* __restrict__ out)
{
    __shared__ __bf16 As[64][32];
    __shared__ __bf16 Bs[64][32];
    int r0 = blockIdx.x*64, c0 = blockIdx.y*64;
    int tid = threadIdx.x;
    int wv = tid >> 6, lane = tid & 63, quad = lane >> 4, mn = lane & 15;
    int sr = tid >> 2, sc = (tid & 3) * 8;

    f32x4 acc[4];
    #pragma unroll
    for (int ct = 0; ct < 4; ++ct)
        #pragma unroll
        for (int rr = 0; rr < 4; ++rr) acc[ct][rr] = 0.f;

    for (int kc = 0; kc < 8; ++kc) {
        __syncthreads();
        {
            int gr = r0 + sr;
            float v[8];
            if (gr < M_) {
                float4 f1 = *(const float4*)&A[(size_t)gr*256 + kc*32 + sc];
                float4 f2 = *(const float4*)&A[(size_t)gr*256 + kc*32 + sc + 4];
                v[0]=f1.x; v[1]=f1.y; v[2]=f1.z; v[3]=f1.w;
                v[4]=f2.x; v[5]=f2.y; v[6]=f2.z; v[7]=f2.w;
            } else {
                #pragma unroll
                for (int i = 0; i < 8; ++i) v[i] = 0.f;
            }
            bf16x8 bv;
            #pragma unroll
            for (int i = 0; i < 8; ++i) bv[i] = (__bf16)v[i];
            *(bf16x8*)&As[sr][sc] = bv;
            *(uint4*)&Bs[sr][sc] = *(const uint4*)&Wt[(size_t)(c0+sr)*256 + kc*32 + sc];
        }
        __syncthreads();

        bf16x8 a = *(const bf16x8*)&As[wv*16 + mn][quad*8];
        #pragma unroll
        for (int ct = 0; ct < 4; ++ct) {
            bf16x8 b = *(const bf16x8*)&Bs[ct*16 + mn][quad*8];
            acc[ct] = __builtin_amdgcn_mfma_f32_16x16x32_bf16(a, b, acc[ct], 0, 0, 0);
        }
    }

    #pragma unroll
    for (int ct = 0; ct < 4; ++ct) {
        int col = c0 + ct*16 + mn;
        #pragma unroll
        for (int rr = 0; rr < 4; ++rr) {
            int row = r0 + wv*16 + quad*4 + rr;
            if (row >= M_) continue;
            float val = acc[ct][rr];
            if (BIAS) val += bias[col];
            if (GELU) val = 0.5f*val*(1.f + erff(val*0.70710678118654752f));
            size_t oi = (size_t)row*NC + col;
            if (ADD) out[oi] += val; else out[oi] = val;
        }
    }
}

// ---------------------------------------------------------------------------
// qkv GEMM: same 64x64 MFMA core over [M,768], epilogue packs bf16:
//   qB[b,h,n,32] (scaled), kB[b,h,n,32], vB[b,h,32,n] (transposed).
// ---------------------------------------------------------------------------
__global__ __launch_bounds__(256) void gemm_qkv(
    const float* __restrict__ A, const __bf16* __restrict__ Wt,
    __bf16* __restrict__ qB, __bf16* __restrict__ kB, __bf16* __restrict__ vB)
{
    __shared__ __bf16 As[64][32];
    __shared__ __bf16 Bs[64][32];
    int r0 = blockIdx.x*64, c0 = blockIdx.y*64;
    int tid = threadIdx.x;
    int wv = tid >> 6, lane = tid & 63, quad = lane >> 4, mn = lane & 15;
    int sr = tid >> 2, sc = (tid & 3) * 8;

    f32x4 acc[4];
    #pragma unroll
    for (int ct = 0; ct < 4; ++ct)
        #pragma unroll
        for (int rr = 0; rr < 4; ++rr) acc[ct][rr] = 0.f;

    for (int kc = 0; kc < 8; ++kc) {
        __syncthreads();
        {
            int gr = r0 + sr;
            float v[8];
            if (gr < M_) {
                float4 f1 = *(const float4*)&A[(size_t)gr*256 + kc*32 + sc];
                float4 f2 = *(const float4*)&A[(size_t)gr*256 + kc*32 + sc + 4];
                v[0]=f1.x; v[1]=f1.y; v[2]=f1.z; v[3]=f1.w;
                v[4]=f2.x; v[5]=f2.y; v[6]=f2.z; v[7]=f2.w;
            } else {
                #pragma unroll
                for (int i = 0; i < 8; ++i) v[i] = 0.f;
            }
            bf16x8 bv;
            #pragma unroll
            for (int i = 0; i < 8; ++i) bv[i] = (__bf16)v[i];
            *(bf16x8*)&As[sr][sc] = bv;
            *(uint4*)&Bs[sr][sc] = *(const uint4*)&Wt[(size_t)(c0+sr)*256 + kc*32 + sc];
        }
        __syncthreads();

        bf16x8 a = *(const bf16x8*)&As[wv*16 + mn][quad*8];
        #pragma unroll
        for (int ct = 0; ct < 4; ++ct) {
            bf16x8 b = *(const bf16x8*)&Bs[ct*16 + mn][quad*8];
            acc[ct] = __builtin_amdgcn_mfma_f32_16x16x32_bf16(a, b, acc[ct], 0, 0, 0);
        }
    }

    const float scale = 0.17677669529663687f;   // 1/sqrt(32)
    #pragma unroll
    for (int ct = 0; ct < 4; ++ct) {
        int col = c0 + ct*16 + mn;
        #pragma unroll
        for (int rr = 0; rr < 4; ++rr) {
            int row = r0 + wv*16 + quad*4 + rr;
            if (row >= M_) continue;
            int b = row / N_, n = row - b*N_;
            float val = acc[ct][rr];
            if (col < 256) {
                int h = col >> 5, dd = col & 31;
                qB[((size_t)(b*NH_+h)*NPAD + n)*32 + dd] = (__bf16)(val*scale);
            } else if (col < 512) {
                int h = (col-256) >> 5, dd = col & 31;
                kB[((size_t)(b*NH_+h)*NPAD + n)*32 + dd] = (__bf16)val;
            } else {
                int h = (col-512) >> 5, dd = col & 31;
                vB[((size_t)(b*NH_+h)*32 + dd)*NPAD + n] = (__bf16)val;
            }
        }
    }
}

// ---------------------------------------------------------------------------
// attn5: MFMA flash attention. Block = (64 q, head, batch), 4 waves.
// Wave wv owns q-rows [wv*16, wv*16+16). Per 64-key tile:
//   S (4 mfma) -> fp32 online softmax in C/D layout -> P bf16 via LDS
//   round-trip -> PV (4 mfma) into fp32 acc.
// Layouts (verified): A/B frag [m|n=lane&15][k=quad*8+j]; C/D row=quad*4+reg,
// col=lane&15.
// ---------------------------------------------------------------------------
__global__ __launch_bounds__(256) void attn5(
    const __bf16* __restrict__ qB, const __bf16* __restrict__ kB,
    const __bf16* __restrict__ vB, float* __restrict__ o)
{
    int q0 = blockIdx.x * 64;
    int h  = blockIdx.y, b = blockIdx.z, bh = b*NH_ + h;
    int tid = threadIdx.x;
    int wv = tid >> 6, lane = tid & 63, quad = lane >> 4, mn = lane & 15;

    __shared__ __align__(16) __bf16 lk[64*32];      // [key][d] dense
    __shared__ __align__(16) __bf16 lvt[32*80];     // [d][key] stride 80
    __shared__ __align__(16) __bf16 lp[4][16*80];   // per-wave P [qrel][key] stride 80

    bf16x8 qfrag = *(const bf16x8*)(
        qB + ((size_t)bh*NPAD + q0 + wv*16 + mn)*32 + quad*8);

    f32x4 oacc0, oacc1;
    #pragma unroll
    for (int rr = 0; rr < 4; ++rr) { oacc0[rr] = 0.f; oacc1[rr] = 0.f; }
    float mrow[4] = {-1e30f,-1e30f,-1e30f,-1e30f};
    float lrow[4] = {0.f,0.f,0.f,0.f};

    const __bf16* kbase = kB + (size_t)bh*NPAD*32;
    const __bf16* vbase = vB + (size_t)bh*32*NPAD;

    for (int t = 0; t < 28; ++t) {
        int k0 = t*64;
        __syncthreads();
        {   // stage K tile (contiguous 4KB) + V^T tile
            bf16x8 kv = *(const bf16x8*)(kbase + (size_t)k0*32 + wv*512 + lane*8);
            *(bf16x8*)&lk[wv*512 + lane*8] = kv;
            int d  = wv*8 + (lane >> 3);
            int ch = lane & 7;
            bf16x8 vv = *(const bf16x8*)(vbase + (size_t)d*NPAD + k0 + ch*8);
            *(bf16x8*)&lvt[d*80 + ch*8] = vv;
        }
        __syncthreads();

        // S = Q K^T  (fp32 accum)
        f32x4 s[4];
        #pragma unroll
        for (int ct = 0; ct < 4; ++ct) {
            bf16x8 kf = *(const bf16x8*)&lk[(ct*16 + mn)*32 + quad*8];
            f32x4 z;
            #pragma unroll
            for (int rr = 0; rr < 4; ++rr) z[rr] = 0.f;
            s[ct] = __builtin_amdgcn_mfma_f32_16x16x32_bf16(qfrag, kf, z, 0, 0, 0);
            if (k0 + mn + 16*ct >= N_) {
                #pragma unroll
                for (int rr = 0; rr < 4; ++rr) s[ct][rr] = -1e30f;
            }
        }

        // row max (across mn lanes)
        float tm[4];
        #pragma unroll
        for (int rr = 0; rr < 4; ++rr)
            tm[rr] = fmaxf(fmaxf(s[0][rr], s[1][rr]), fmaxf(s[2][rr], s[3][rr]));
        #pragma unroll
        for (int msk = 1; msk < 16; msk <<= 1)
            #pragma unroll
            for (int rr = 0; rr < 4; ++rr)
                tm[rr] = fmaxf(tm[rr], __shfl_xor(tm[rr], msk));

        float al[4];
        #pragma unroll
        for (int rr = 0; rr < 4; ++rr) {
            float mnew = fmaxf(mrow[rr], tm[rr]);
            al[rr] = __expf(mrow[rr] - mnew);
            mrow[rr] = mnew;
        }

        // P = exp(S - m), write to per-wave LDS (C/D -> A-frag round trip)
        #pragma unroll
        for (int ct = 0; ct < 4; ++ct)
            #pragma unroll
            for (int rr = 0; rr < 4; ++rr) {
                float p = __expf(s[ct][rr] - mrow[rr]);
                s[ct][rr] = p;
                lp[wv][(quad*4+rr)*80 + ct*16 + mn] = (__bf16)p;
            }

        float rs[4];
        #pragma unroll
        for (int rr = 0; rr < 4; ++rr)
            rs[rr] = (s[0][rr] + s[1][rr]) + (s[2][rr] + s[3][rr]);
        #pragma unroll
        for (int msk = 1; msk < 16; msk <<= 1)
            #pragma unroll
            for (int rr = 0; rr < 4; ++rr)
                rs[rr] += __shfl_xor(rs[rr], msk);

        #pragma unroll
        for (int rr = 0; rr < 4; ++rr) {
            lrow[rr] = lrow[rr]*al[rr] + rs[rr];
            oacc0[rr] *= al[rr];
            oacc1[rr] *= al[rr];
        }

        // O += P V  (K-dim 64 -> 2 halves; d 32 -> 2 col-tiles)
        #pragma unroll
        for (int kh = 0; kh < 2; ++kh) {
            bf16x8 pf = *(const bf16x8*)&lp[wv][mn*80 + kh*32 + quad*8];
            bf16x8 v0 = *(const bf16x8*)&lvt[ mn      *80 + kh*32 + quad*8];
            bf16x8 v1 = *(const bf16x8*)&lvt[(mn+16)*80 + kh*32 + quad*8];
            oacc0 = __builtin_amdgcn_mfma_f32_16x16x32_bf16(pf, v0, oacc0, 0, 0, 0);
            oacc1 = __builtin_amdgcn_mfma_f32_16x16x32_bf16(pf, v1, oacc1, 0, 0, 0);
        }
    }

    #pragma unroll
    for (int rr = 0; rr < 4; ++rr) {
        int q = q0 + wv*16 + quad*4 + rr;
        if (q >= N_) continue;
        float inv = 1.0f / lrow[rr];
        size_t base = ((size_t)(b*N_ + q))*C_ + h*HD_;
        o[base + mn]      = oacc0[rr]*inv;
        o[base + 16 + mn] = oacc1[rr]*inv;
    }
}

// ---------------------------------------------------------------------------
// feat: out_feat[(b*256+c)*1728 + p] = y[(b*1729 + 1 + p)*256 + c]  (fp32)
// ---------------------------------------------------------------------------
__global__ __launch_bounds__(256) void feat2(
    const float* __restrict__ y, float* __restrict__ outf)
{
    int idx  = blockIdx.x*256 + threadIdx.x;   // [0, B*C*P)
    int p    = idx % P_;
    int rest = idx / P_;
    int c    = rest % C_;
    int b    = rest / C_;
    outf[idx] = y[((size_t)(b*N_) + 1 + p)*C_ + c];
}

// ---------------------------------------------------------------------------
extern "C" void kernel_launch(void* const* d_in, const int* in_sizes, int n_in,
                              void* d_out, int out_size, void* d_ws, size_t ws_size,
                              hipStream_t stream)
{
    const float* x        = (const float*)d_in[0];
    const float* W_pe     = (const float*)d_in[1];
    const float* b_pe     = (const float*)d_in[2];
    const float* cls_tok  = (const float*)d_in[3];
    const float* ln1_g    = (const float*)d_in[4];
    const float* ln1_b    = (const float*)d_in[5];
    const float* Wqkv     = (const float*)d_in[6];
    const float* Wproj    = (const float*)d_in[7];
    const float* bproj    = (const float*)d_in[8];
    const float* ln2_g    = (const float*)d_in[9];
    const float* ln2_b    = (const float*)d_in[10];
    const float* W1       = (const float*)d_in[11];
    const float* b1       = (const float*)d_in[12];
    const float* W2       = (const float*)d_in[13];
    const float* b2       = (const float*)d_in[14];
    const float* normf_g  = (const float*)d_in[15];
    const float* normf_b  = (const float*)d_in[16];

    const size_t MC = (size_t)M_*C_;
    float* ws   = (float*)d_ws;
    float* t    = ws;                       // M*256 fp32
    float* y    = ws + MC;                  // M*256 fp32
    float* hbuf = ws + 2*MC;                // M*256 fp32 (MLP hidden)

    __bf16* wT   = (__bf16*)(ws + 3*MC);
    __bf16* qkvT = wT;                      // 2 x 768*256
    __bf16* projT = wT + 2*768*256;         // 2 x 256*256
    __bf16* w1T   = projT + 2*256*256;
    __bf16* w2T   = w1T   + 2*256*256;
    // packed attention operands (bf16)
    __bf16* qB = (__bf16*)(ws + 3*MC + 393216);        // [4*8][NPAD][32]
    __bf16* kB = qB + (size_t)B_*NH_*NPAD*32;
    __bf16* vB = kB + (size_t)B_*NH_*NPAD*32;          // [4*8][32][NPAD]

    float* out_cls  = (float*)d_out;        // 4*256 fp32
    float* out_feat = out_cls + B_*C_;      // 4*256*1728 fp32

    for (int i = 0; i < 2; ++i) {
        wprep<<<dim3(768/32, 8), 256, 0, stream>>>(Wqkv + (size_t)i*C_*768, qkvT + (size_t)i*768*256, 768);
        wprep<<<dim3(256/32, 8), 256, 0, stream>>>(Wproj + (size_t)i*C_*C_, projT + (size_t)i*256*256, 256);
        wprep<<<dim3(256/32, 8), 256, 0, stream>>>(W1 + (size_t)i*C_*C_, w1T + (size_t)i*256*256, 256);
        wprep<<<dim3(256/32, 8), 256, 0, stream>>>(W2 + (size_t)i*C_*C_, w2T + (size_t)i*256*256, 256);
    }

    embed2<<<(B_*N_*C_)/256, 256, 0, stream>>>(x, W_pe, b_pe, cls_tok, t);

    const int GRID_M = (M_ + 63) / 64;   // 109
    for (int i = 0; i < 2; ++i) {
        ln2<<<M_, 256, 0, stream>>>(t, y, ln1_g + i*C_, ln1_b + i*C_, nullptr);
        gemm_qkv<<<dim3(GRID_M, 12), 256, 0, stream>>>(
            y, qkvT + (size_t)i*768*256, qB, kB, vB);
        attn5<<<dim3(28, NH_, B_), 256, 0, stream>>>(qB, kB, vB, y);
        gemm_mfma<256,true,false,true><<<dim3(GRID_M, 4), 256, 0, stream>>>(
            y, projT + (size_t)i*256*256, bproj + i*C_, t);
        ln2<<<M_, 256, 0, stream>>>(t, y, ln2_g + i*C_, ln2_b + i*C_, nullptr);
        gemm_mfma<256,false,true,true><<<dim3(GRID_M, 4), 256, 0, stream>>>(
            y, w1T + (size_t)i*256*256, b1 + i*C_, hbuf);
        gemm_mfma<256,true,false,true><<<dim3(GRID_M, 4), 256, 0, stream>>>(
            hbuf, w2T + (size_t)i*256*256, b2 + i*C_, t);
    }

    ln2<<<M_, 256, 0, stream>>>(t, y, normf_g, normf_b, out_cls);
    feat2<<<(B_*C_*P_)/256, 256, 0, stream>>>(y, out_feat);
}

// Round 10
// 388.593 us; speedup vs baseline: 13.2181x; 1.2054x over previous
//
#include <hip/hip_runtime.h>
#include <hip/hip_bf16.h>
#include <math.h>

#define B_   4
#define CIN  64
#define P_   1728
#define N_   1729
#define C_   256
#define NH_  8
#define HD_  32
#define M_   (B_*N_)   // 6916 rows
#define NPAD 1792      // 28 * 64

typedef __bf16 bf16x8 __attribute__((ext_vector_type(8)));
typedef float  f32x4  __attribute__((ext_vector_type(4)));

// ---------------------------------------------------------------------------
// Patch embed. One thread per (b, n, c).
// ---------------------------------------------------------------------------
__global__ __launch_bounds__(256) void embed2(
    const float* __restrict__ x, const float* __restrict__ Wpe,
    const float* __restrict__ bpe, const float* __restrict__ cls,
    float* __restrict__ t)
{
    int idx = blockIdx.x*256 + threadIdx.x;        // [0, B*N*C)
    int c   = idx & 255;
    int n   = (idx >> 8) % N_;
    int b   = idx / (N_*256);
    if (n == 0) { t[idx] = cls[c]; return; }
    int p = n - 1;
    float acc = bpe[c];
    for (int ci = 0; ci < CIN; ++ci)
        acc += x[(size_t)(b*CIN + ci)*P_ + p] * Wpe[ci*C_ + c];
    t[idx] = acc;
}

// ---------------------------------------------------------------------------
// ln3: LayerNorm over C=256, single-pass (E[x^2]-m^2), wave shuffles,
// 1 barrier. One block (256 thr = 4 waves) per row.
// ---------------------------------------------------------------------------
__global__ __launch_bounds__(256) void ln3(
    const float* __restrict__ in, float* __restrict__ out,
    const float* __restrict__ g, const float* __restrict__ bb,
    float* __restrict__ cls_out)
{
    int row = blockIdx.x;
    int c   = threadIdx.x;
    float v = in[(size_t)row*C_ + c];
    float s1 = v, s2 = v*v;
    #pragma unroll
    for (int off = 32; off >= 1; off >>= 1) {
        s1 += __shfl_xor(s1, off);
        s2 += __shfl_xor(s2, off);
    }
    __shared__ float r1[4], r2[4];
    if ((c & 63) == 0) { r1[c>>6] = s1; r2[c>>6] = s2; }
    __syncthreads();
    s1 = (r1[0]+r1[1]) + (r1[2]+r1[3]);
    s2 = (r2[0]+r2[1]) + (r2[2]+r2[3]);
    float mean = s1 * (1.0f/C_);
    float var  = fmaxf(s2 * (1.0f/C_) - mean*mean, 0.0f);
    float rstd = rsqrtf(var + 1e-5f);
    float val  = (v - mean) * rstd * g[c] + bb[c];
    out[(size_t)row*C_ + c] = val;
    if (cls_out && (row % N_) == 0)
        cls_out[(row / N_)*C_ + c] = val;
}

// ---------------------------------------------------------------------------
// Weight prep: Wt[n][k] = bf16(W[k][n]).
// ---------------------------------------------------------------------------
__global__ __launch_bounds__(256) void wprep(
    const float* __restrict__ W, __bf16* __restrict__ Wt, int NC)
{
    __shared__ float tile[32][33];
    int n0 = blockIdx.x*32, k0 = blockIdx.y*32;
    int c = threadIdx.x & 31, r = threadIdx.x >> 5;
    for (int rr = r; rr < 32; rr += 8)
        tile[rr][c] = W[(size_t)(k0+rr)*NC + n0 + c];
    __syncthreads();
    for (int rr = r; rr < 32; rr += 8)
        Wt[(size_t)(n0+rr)*256 + k0 + c] = (__bf16)tile[c][rr];
}

// ---------------------------------------------------------------------------
// MFMA GEMM: out[M,NC] (+)= A[M,256] @ W[256,NC] (+bias)(gelu). 64x64 tile.
// ---------------------------------------------------------------------------
template<int NC, bool ADD, bool GELU, bool BIAS>
__global__ __launch_bounds__(256) void gemm_mfma(
    const float* __restrict__ A, const __bf16* __restrict__ Wt,
    const float* __restrict__ bias, float* __restrict__ out)
{
    __shared__ __bf16 As[64][32];
    __shared__ __bf16 Bs[64][32];
    int r0 = blockIdx.x*64, c0 = blockIdx.y*64;
    int tid = threadIdx.x;
    int wv = tid >> 6, lane = tid & 63, quad = lane >> 4, mn = lane & 15;
    int sr = tid >> 2, sc = (tid & 3) * 8;

    f32x4 acc[4];
    #pragma unroll
    for (int ct = 0; ct < 4; ++ct)
        #pragma unroll
        for (int rr = 0; rr < 4; ++rr) acc[ct][rr] = 0.f;

    for (int kc = 0; kc < 8; ++kc) {
        __syncthreads();
        {
            int gr = r0 + sr;
            float v[8];
            if (gr < M_) {
                float4 f1 = *(const float4*)&A[(size_t)gr*256 + kc*32 + sc];
                float4 f2 = *(const float4*)&A[(size_t)gr*256 + kc*32 + sc + 4];
                v[0]=f1.x; v[1]=f1.y; v[2]=f1.z; v[3]=f1.w;
                v[4]=f2.x; v[5]=f2.y; v[6]=f2.z; v[7]=f2.w;
            } else {
                #pragma unroll
                for (int i = 0; i < 8; ++i) v[i] = 0.f;
            }
            bf16x8 bv;
            #pragma unroll
            for (int i = 0; i < 8; ++i) bv[i] = (__bf16)v[i];
            *(bf16x8*)&As[sr][sc] = bv;
            *(uint4*)&Bs[sr][sc] = *(const uint4*)&Wt[(size_t)(c0+sr)*256 + kc*32 + sc];
        }
        __syncthreads();

        bf16x8 a = *(const bf16x8*)&As[wv*16 + mn][quad*8];
        #pragma unroll
        for (int ct = 0; ct < 4; ++ct) {
            bf16x8 b = *(const bf16x8*)&Bs[ct*16 + mn][quad*8];
            acc[ct] = __builtin_amdgcn_mfma_f32_16x16x32_bf16(a, b, acc[ct], 0, 0, 0);
        }
    }

    #pragma unroll
    for (int ct = 0; ct < 4; ++ct) {
        int col = c0 + ct*16 + mn;
        #pragma unroll
        for (int rr = 0; rr < 4; ++rr) {
            int row = r0 + wv*16 + quad*4 + rr;
            if (row >= M_) continue;
            float val = acc[ct][rr];
            if (BIAS) val += bias[col];
            if (GELU) val = 0.5f*val*(1.f + erff(val*0.70710678118654752f));
            size_t oi = (size_t)row*NC + col;
            if (ADD) out[oi] += val; else out[oi] = val;
        }
    }
}

// ---------------------------------------------------------------------------
// qkv GEMM: MFMA core over [M,768], epilogue packs bf16:
//   qB[b,h,n,32] (scaled), kB[b,h,n,32], vB[b,h,32,n] (transposed).
// ---------------------------------------------------------------------------
__global__ __launch_bounds__(256) void gemm_qkv(
    const float* __restrict__ A, const __bf16* __restrict__ Wt,
    __bf16* __restrict__ qB, __bf16* __restrict__ kB, __bf16* __restrict__ vB)
{
    __shared__ __bf16 As[64][32];
    __shared__ __bf16 Bs[64][32];
    int r0 = blockIdx.x*64, c0 = blockIdx.y*64;
    int tid = threadIdx.x;
    int wv = tid >> 6, lane = tid & 63, quad = lane >> 4, mn = lane & 15;
    int sr = tid >> 2, sc = (tid & 3) * 8;

    f32x4 acc[4];
    #pragma unroll
    for (int ct = 0; ct < 4; ++ct)
        #pragma unroll
        for (int rr = 0; rr < 4; ++rr) acc[ct][rr] = 0.f;

    for (int kc = 0; kc < 8; ++kc) {
        __syncthreads();
        {
            int gr = r0 + sr;
            float v[8];
            if (gr < M_) {
                float4 f1 = *(const float4*)&A[(size_t)gr*256 + kc*32 + sc];
                float4 f2 = *(const float4*)&A[(size_t)gr*256 + kc*32 + sc + 4];
                v[0]=f1.x; v[1]=f1.y; v[2]=f1.z; v[3]=f1.w;
                v[4]=f2.x; v[5]=f2.y; v[6]=f2.z; v[7]=f2.w;
            } else {
                #pragma unroll
                for (int i = 0; i < 8; ++i) v[i] = 0.f;
            }
            bf16x8 bv;
            #pragma unroll
            for (int i = 0; i < 8; ++i) bv[i] = (__bf16)v[i];
            *(bf16x8*)&As[sr][sc] = bv;
            *(uint4*)&Bs[sr][sc] = *(const uint4*)&Wt[(size_t)(c0+sr)*256 + kc*32 + sc];
        }
        __syncthreads();

        bf16x8 a = *(const bf16x8*)&As[wv*16 + mn][quad*8];
        #pragma unroll
        for (int ct = 0; ct < 4; ++ct) {
            bf16x8 b = *(const bf16x8*)&Bs[ct*16 + mn][quad*8];
            acc[ct] = __builtin_amdgcn_mfma_f32_16x16x32_bf16(a, b, acc[ct], 0, 0, 0);
        }
    }

    const float scale = 0.17677669529663687f;   // 1/sqrt(32)
    #pragma unroll
    for (int ct = 0; ct < 4; ++ct) {
        int col = c0 + ct*16 + mn;
        #pragma unroll
        for (int rr = 0; rr < 4; ++rr) {
            int row = r0 + wv*16 + quad*4 + rr;
            if (row >= M_) continue;
            int b = row / N_, n = row - b*N_;
            float val = acc[ct][rr];
            if (col < 256) {
                int h = col >> 5, dd = col & 31;
                qB[((size_t)(b*NH_+h)*NPAD + n)*32 + dd] = (__bf16)(val*scale);
            } else if (col < 512) {
                int h = (col-256) >> 5, dd = col & 31;
                kB[((size_t)(b*NH_+h)*NPAD + n)*32 + dd] = (__bf16)val;
            } else {
                int h = (col-512) >> 5, dd = col & 31;
                vB[((size_t)(b*NH_+h)*32 + dd)*NPAD + n] = (__bf16)val;
            }
        }
    }
}

// ---------------------------------------------------------------------------
// attn6: MFMA flash attention, no-max softmax (|s|<~2 by construction),
// l accumulated via ones-column in V^T (3rd PV n-tile). Conflict-light LDS
// strides (lk 36, lvt/lp 76). Grid (bh, qtile) for K/V L2 locality.
// FIX vs R9: V^T staging now covers all 64 key columns (32 rows x 8 chunks,
// 256 threads); R9 covered only cols 0..31 -> uninitialized LDS -> NaN.
// ---------------------------------------------------------------------------
__global__ __launch_bounds__(256) void attn6(
    const __bf16* __restrict__ qB, const __bf16* __restrict__ kB,
    const __bf16* __restrict__ vB, float* __restrict__ o)
{
    int bh = blockIdx.x, b = bh >> 3, h = bh & 7;
    int q0 = blockIdx.y * 64;
    int tid = threadIdx.x;
    int wv = tid >> 6, lane = tid & 63, quad = lane >> 4, mn = lane & 15;

    __shared__ __align__(16) __bf16 lk[64*36];       // [key][d], stride 36
    __shared__ __align__(16) __bf16 lvt[48*76];      // [d][key], stride 76; row32=ones, 33..47=0
    __shared__ __align__(16) __bf16 lp[4][16*76];    // per-wave P [q][key], stride 76

    // static rows of lvt (ones row + zero rows) — written once
    for (int e = tid; e < 16*76; e += 256)
        lvt[32*76 + e] = (e < 76) ? (__bf16)1.0f : (__bf16)0.0f;

    bf16x8 qfrag = *(const bf16x8*)(
        qB + ((size_t)bh*NPAD + q0 + wv*16 + mn)*32 + quad*8);

    f32x4 oacc0, oacc1, oacc2;
    #pragma unroll
    for (int rr = 0; rr < 4; ++rr) { oacc0[rr]=0.f; oacc1[rr]=0.f; oacc2[rr]=0.f; }

    const __bf16* kbase = kB + (size_t)bh*NPAD*32;
    const __bf16* vbase = vB + (size_t)bh*32*NPAD;
    int sr = tid >> 2, sc8 = (tid & 3) * 8;          // K staging: 64 rows x 4 chunks
    int vr = tid >> 3, vc8 = (tid & 7) * 8;          // V^T staging: 32 rows x 8 chunks

    for (int t = 0; t < 28; ++t) {
        int k0 = t*64;
        __syncthreads();
        // stage K [64][32] -> lk stride 36 ; V^T [32][64] -> lvt stride 76
        *(bf16x8*)&lk[sr*36 + sc8] =
            *(const bf16x8*)(kbase + (size_t)(k0 + sr)*32 + sc8);
        *(bf16x8*)&lvt[vr*76 + vc8] =
            *(const bf16x8*)(vbase + (size_t)vr*NPAD + k0 + vc8);
        __syncthreads();

        // S = Q K^T
        f32x4 s[4];
        #pragma unroll
        for (int ct = 0; ct < 4; ++ct) {
            bf16x8 kf = *(const bf16x8*)&lk[(ct*16 + mn)*36 + quad*8];
            f32x4 z;
            #pragma unroll
            for (int rr = 0; rr < 4; ++rr) z[rr] = 0.f;
            s[ct] = __builtin_amdgcn_mfma_f32_16x16x32_bf16(qfrag, kf, z, 0, 0, 0);
        }

        // P = exp(S), masked for invalid keys; store to per-wave LDS
        #pragma unroll
        for (int ct = 0; ct < 4; ++ct) {
            bool valid = (k0 + ct*16 + mn) < N_;
            #pragma unroll
            for (int rr = 0; rr < 4; ++rr) {
                float p = valid ? __expf(s[ct][rr]) : 0.f;
                lp[wv][(quad*4+rr)*76 + ct*16 + mn] = (__bf16)p;
            }
        }
        // wave-local: no barrier needed before reading lp

        // O += P V  (+ l via ones-tile)
        #pragma unroll
        for (int kh = 0; kh < 2; ++kh) {
            bf16x8 pf = *(const bf16x8*)&lp[wv][mn*76 + kh*32 + quad*8];
            bf16x8 v0 = *(const bf16x8*)&lvt[ mn      *76 + kh*32 + quad*8];
            bf16x8 v1 = *(const bf16x8*)&lvt[(mn+16)*76 + kh*32 + quad*8];
            bf16x8 v2 = *(const bf16x8*)&lvt[(mn+32)*76 + kh*32 + quad*8];
            oacc0 = __builtin_amdgcn_mfma_f32_16x16x32_bf16(pf, v0, oacc0, 0, 0, 0);
            oacc1 = __builtin_amdgcn_mfma_f32_16x16x32_bf16(pf, v1, oacc1, 0, 0, 0);
            oacc2 = __builtin_amdgcn_mfma_f32_16x16x32_bf16(pf, v2, oacc2, 0, 0, 0);
        }
    }

    #pragma unroll
    for (int rr = 0; rr < 4; ++rr) {
        float l = __shfl(oacc2[rr], lane & 48);   // ones-col (d=32) lives in mn==0 lane of this quad
        int q = q0 + wv*16 + quad*4 + rr;
        if (q >= N_) continue;
        float inv = 1.0f / l;
        size_t base = ((size_t)(b*N_ + q))*C_ + h*HD_;
        o[base + mn]      = oacc0[rr]*inv;
        o[base + 16 + mn] = oacc1[rr]*inv;
    }
}

// ---------------------------------------------------------------------------
// feat3: LDS 32x32 tile transpose. grid (54, 8, 4).
// out_feat[(b*256+c)*1728 + p] = y[(b*1729 + 1 + p)*256 + c]
// ---------------------------------------------------------------------------
__global__ __launch_bounds__(256) void feat3(
    const float* __restrict__ y, float* __restrict__ outf)
{
    __shared__ float tl[32][33];
    int p0 = blockIdx.x*32, c0 = blockIdx.y*32, b = blockIdx.z;
    int cc = threadIdx.x & 31, rr = threadIdx.x >> 5;   // 8 rows/pass
    for (int i = rr; i < 32; i += 8)
        tl[i][cc] = y[((size_t)(b*N_) + 1 + p0 + i)*C_ + c0 + cc];
    __syncthreads();
    for (int i = rr; i < 32; i += 8)
        outf[((size_t)(b*C_) + c0 + i)*P_ + p0 + cc] = tl[cc][i];
}

// ---------------------------------------------------------------------------
extern "C" void kernel_launch(void* const* d_in, const int* in_sizes, int n_in,
                              void* d_out, int out_size, void* d_ws, size_t ws_size,
                              hipStream_t stream)
{
    const float* x        = (const float*)d_in[0];
    const float* W_pe     = (const float*)d_in[1];
    const float* b_pe     = (const float*)d_in[2];
    const float* cls_tok  = (const float*)d_in[3];
    const float* ln1_g    = (const float*)d_in[4];
    const float* ln1_b    = (const float*)d_in[5];
    const float* Wqkv     = (const float*)d_in[6];
    const float* Wproj    = (const float*)d_in[7];
    const float* bproj    = (const float*)d_in[8];
    const float* ln2_g    = (const float*)d_in[9];
    const float* ln2_b    = (const float*)d_in[10];
    const float* W1       = (const float*)d_in[11];
    const float* b1       = (const float*)d_in[12];
    const float* W2       = (const float*)d_in[13];
    const float* b2       = (const float*)d_in[14];
    const float* normf_g  = (const float*)d_in[15];
    const float* normf_b  = (const float*)d_in[16];

    const size_t MC = (size_t)M_*C_;
    float* ws   = (float*)d_ws;
    float* t    = ws;                       // M*256 fp32
    float* y    = ws + MC;                  // M*256 fp32
    float* hbuf = ws + 2*MC;                // M*256 fp32 (MLP hidden)

    __bf16* wT    = (__bf16*)(ws + 3*MC);
    __bf16* qkvT  = wT;                     // 2 x 768*256
    __bf16* projT = wT + 2*768*256;
    __bf16* w1T   = projT + 2*256*256;
    __bf16* w2T   = w1T   + 2*256*256;
    __bf16* qB = (__bf16*)(ws + 3*MC + 393216);        // [32][NPAD][32]
    __bf16* kB = qB + (size_t)B_*NH_*NPAD*32;
    __bf16* vB = kB + (size_t)B_*NH_*NPAD*32;          // [32][32][NPAD]

    float* out_cls  = (float*)d_out;
    float* out_feat = out_cls + B_*C_;

    for (int i = 0; i < 2; ++i) {
        wprep<<<dim3(768/32, 8), 256, 0, stream>>>(Wqkv + (size_t)i*C_*768, qkvT + (size_t)i*768*256, 768);
        wprep<<<dim3(256/32, 8), 256, 0, stream>>>(Wproj + (size_t)i*C_*C_, projT + (size_t)i*256*256, 256);
        wprep<<<dim3(256/32, 8), 256, 0, stream>>>(W1 + (size_t)i*C_*C_, w1T + (size_t)i*256*256, 256);
        wprep<<<dim3(256/32, 8), 256, 0, stream>>>(W2 + (size_t)i*C_*C_, w2T + (size_t)i*256*256, 256);
    }

    embed2<<<(B_*N_*C_)/256, 256, 0, stream>>>(x, W_pe, b_pe, cls_tok, t);

    const int GRID_M = (M_ + 63) / 64;   // 109
    for (int i = 0; i < 2; ++i) {
        ln3<<<M_, 256, 0, stream>>>(t, y, ln1_g + i*C_, ln1_b + i*C_, nullptr);
        gemm_qkv<<<dim3(GRID_M, 12), 256, 0, stream>>>(
            y, qkvT + (size_t)i*768*256, qB, kB, vB);
        attn6<<<dim3(32, 28), 256, 0, stream>>>(qB, kB, vB, y);
        gemm_mfma<256,true,false,true><<<dim3(GRID_M, 4), 256, 0, stream>>>(
            y, projT + (size_t)i*256*256, bproj + i*C_, t);
        ln3<<<M_, 256, 0, stream>>>(t, y, ln2_g + i*C_, ln2_b + i*C_, nullptr);
        gemm_mfma<256,false,true,true><<<dim3(GRID_M, 4), 256, 0, stream>>>(
            y, w1T + (size_t)i*256*256, b1 + i*C_, hbuf);
        gemm_mfma<256,true,false,true><<<dim3(GRID_M, 4), 256, 0, stream>>>(
            hbuf, w2T + (size_t)i*256*256, b2 + i*C_, t);
    }

    ln3<<<M_, 256, 0, stream>>>(t, y, normf_g, normf_b, out_cls);
    feat3<<<dim3(54, 8, 4), 256, 0, stream>>>(y, out_feat);
}

// Round 11
// 322.787 us; speedup vs baseline: 15.9129x; 1.2039x over previous
//
#include <hip/hip_runtime.h>
#include <hip/hip_bf16.h>
#include <math.h>

#define B_   4
#define CIN  64
#define P_   1728
#define N_   1729
#define C_   256
#define NH_  8
#define HD_  32
#define M_   (B_*N_)   // 6916 rows
#define NPAD 1792      // 28 * 64

typedef __bf16 bf16x8 __attribute__((ext_vector_type(8)));
typedef __bf16 bf16x4 __attribute__((ext_vector_type(4)));
typedef float  f32x4  __attribute__((ext_vector_type(4)));

// ---------------------------------------------------------------------------
// Patch embed. One thread per (b, n, c). Writes t fp32.
// ---------------------------------------------------------------------------
__global__ __launch_bounds__(256) void embed2(
    const float* __restrict__ x, const float* __restrict__ Wpe,
    const float* __restrict__ bpe, const float* __restrict__ cls,
    float* __restrict__ t)
{
    int idx = blockIdx.x*256 + threadIdx.x;        // [0, B*N*C)
    int c   = idx & 255;
    int n   = (idx >> 8) % N_;
    int b   = idx / (N_*256);
    if (n == 0) { t[idx] = cls[c]; return; }
    int p = n - 1;
    float acc = bpe[c];
    for (int ci = 0; ci < CIN; ++ci)
        acc += x[(size_t)(b*CIN + ci)*P_ + p] * Wpe[ci*C_ + c];
    t[idx] = acc;
}

// ---------------------------------------------------------------------------
// ln4: LayerNorm, 4 rows/block (one wave each), float4 in, bf16x4 out.
// grid = M/4 = 1729.
// ---------------------------------------------------------------------------
__global__ __launch_bounds__(256) void ln4(
    const float* __restrict__ in, __bf16* __restrict__ out,
    const float* __restrict__ g, const float* __restrict__ bb)
{
    int wv = threadIdx.x >> 6, lane = threadIdx.x & 63;
    size_t row = (size_t)blockIdx.x*4 + wv;
    float4 v = *(const float4*)&in[row*C_ + lane*4];
    float s1 = (v.x+v.y)+(v.z+v.w);
    float s2 = (v.x*v.x+v.y*v.y)+(v.z*v.z+v.w*v.w);
    #pragma unroll
    for (int off = 32; off >= 1; off >>= 1) {
        s1 += __shfl_xor(s1, off);
        s2 += __shfl_xor(s2, off);
    }
    float mean = s1*(1.0f/C_);
    float var  = fmaxf(s2*(1.0f/C_) - mean*mean, 0.0f);
    float rstd = rsqrtf(var + 1e-5f);
    float4 gg = *(const float4*)&g[lane*4];
    float4 bv = *(const float4*)&bb[lane*4];
    bf16x4 r;
    r[0] = (__bf16)((v.x-mean)*rstd*gg.x + bv.x);
    r[1] = (__bf16)((v.y-mean)*rstd*gg.y + bv.y);
    r[2] = (__bf16)((v.z-mean)*rstd*gg.z + bv.z);
    r[3] = (__bf16)((v.w-mean)*rstd*gg.w + bv.w);
    *(bf16x4*)&out[row*C_ + lane*4] = r;
}

// ln4f: final norm — fp32 out + cls extraction.
__global__ __launch_bounds__(256) void ln4f(
    const float* __restrict__ in, float* __restrict__ out,
    const float* __restrict__ g, const float* __restrict__ bb,
    float* __restrict__ cls_out)
{
    int wv = threadIdx.x >> 6, lane = threadIdx.x & 63;
    size_t row = (size_t)blockIdx.x*4 + wv;
    float4 v = *(const float4*)&in[row*C_ + lane*4];
    float s1 = (v.x+v.y)+(v.z+v.w);
    float s2 = (v.x*v.x+v.y*v.y)+(v.z*v.z+v.w*v.w);
    #pragma unroll
    for (int off = 32; off >= 1; off >>= 1) {
        s1 += __shfl_xor(s1, off);
        s2 += __shfl_xor(s2, off);
    }
    float mean = s1*(1.0f/C_);
    float var  = fmaxf(s2*(1.0f/C_) - mean*mean, 0.0f);
    float rstd = rsqrtf(var + 1e-5f);
    float4 gg = *(const float4*)&g[lane*4];
    float4 bv = *(const float4*)&bb[lane*4];
    float4 r;
    r.x = (v.x-mean)*rstd*gg.x + bv.x;
    r.y = (v.y-mean)*rstd*gg.y + bv.y;
    r.z = (v.z-mean)*rstd*gg.z + bv.z;
    r.w = (v.w-mean)*rstd*gg.w + bv.w;
    *(float4*)&out[row*C_ + lane*4] = r;
    if ((row % N_) == 0)
        *(float4*)&cls_out[(row / N_)*C_ + lane*4] = r;
}

// ---------------------------------------------------------------------------
// wprep2: all 8 weight matrices -> bf16 W^T[n][k] in one launch.
// grid (24, 8, 8); z = which*2 + layer; which: 0=qkv(NC=768),1=proj,2=W1,3=W2.
// ---------------------------------------------------------------------------
__global__ __launch_bounds__(256) void wprep2(
    const float* __restrict__ Wqkv, const float* __restrict__ Wproj,
    const float* __restrict__ W1,   const float* __restrict__ W2,
    __bf16* __restrict__ wT)
{
    int z = blockIdx.z, which = z >> 1, layer = z & 1;
    const float* src; __bf16* dst; int NC;
    if (which == 0) {
        src = Wqkv + (size_t)layer*C_*768;
        dst = wT   + (size_t)layer*768*256;
        NC  = 768;
    } else {
        NC = 256;
        const float* b3 = (which == 1) ? Wproj : (which == 2) ? W1 : W2;
        src = b3 + (size_t)layer*65536;
        dst = wT + 2*768*256 + (size_t)((which-1)*2 + layer)*65536;
    }
    int n0 = blockIdx.x*32; if (n0 >= NC) return;
    int k0 = blockIdx.y*32;
    __shared__ float tile[32][33];
    int c = threadIdx.x & 31, r = threadIdx.x >> 5;
    for (int rr = r; rr < 32; rr += 8)
        tile[rr][c] = src[(size_t)(k0+rr)*NC + n0 + c];
    __syncthreads();
    for (int rr = r; rr < 32; rr += 8)
        dst[(size_t)(n0+rr)*256 + k0 + c] = (__bf16)tile[c][rr];
}

// ---------------------------------------------------------------------------
// gemm3: out[M,NC] (+)= A[M,256](bf16) @ WtT (+bias fp32)(gelu). 64x64 tile,
// BK=32, LDS stride 40 bf16 (80B: 16B-aligned, 2-way banks on frag reads).
// OUTBF ? bf16 out : fp32 out (with optional +=).
// ---------------------------------------------------------------------------
template<int NC, bool ADD, bool GELU, bool BIAS, bool OUTBF>
__global__ __launch_bounds__(256) void gemm3(
    const __bf16* __restrict__ A, const __bf16* __restrict__ Wt,
    const float* __restrict__ bias, float* __restrict__ outF,
    __bf16* __restrict__ outB)
{
    __shared__ __bf16 As[64*40];
    __shared__ __bf16 Bs[64*40];
    int r0 = blockIdx.x*64, c0 = blockIdx.y*64;
    int tid = threadIdx.x;
    int wv = tid >> 6, lane = tid & 63, quad = lane >> 4, mn = lane & 15;
    int sr = tid >> 2, sc = (tid & 3) * 8;
    int ga = r0 + sr; if (ga >= M_) ga = M_ - 1;   // clamp (epilogue guards)

    f32x4 acc[4];
    #pragma unroll
    for (int ct = 0; ct < 4; ++ct)
        #pragma unroll
        for (int rr = 0; rr < 4; ++rr) acc[ct][rr] = 0.f;

    for (int kc = 0; kc < 8; ++kc) {
        __syncthreads();
        *(bf16x8*)&As[sr*40 + sc] =
            *(const bf16x8*)&A[(size_t)ga*256 + kc*32 + sc];
        *(bf16x8*)&Bs[sr*40 + sc] =
            *(const bf16x8*)&Wt[(size_t)(c0+sr)*256 + kc*32 + sc];
        __syncthreads();

        bf16x8 a = *(const bf16x8*)&As[(wv*16 + mn)*40 + quad*8];
        #pragma unroll
        for (int ct = 0; ct < 4; ++ct) {
            bf16x8 b = *(const bf16x8*)&Bs[(ct*16 + mn)*40 + quad*8];
            acc[ct] = __builtin_amdgcn_mfma_f32_16x16x32_bf16(a, b, acc[ct], 0, 0, 0);
        }
    }

    #pragma unroll
    for (int ct = 0; ct < 4; ++ct) {
        int col = c0 + ct*16 + mn;
        #pragma unroll
        for (int rr = 0; rr < 4; ++rr) {
            int row = r0 + wv*16 + quad*4 + rr;
            if (row >= M_) continue;
            float val = acc[ct][rr];
            if (BIAS) val += bias[col];
            if (GELU) val = 0.5f*val*(1.f + erff(val*0.70710678118654752f));
            size_t oi = (size_t)row*NC + col;
            if (OUTBF) outB[oi] = (__bf16)val;
            else if (ADD) outF[oi] += val;
            else outF[oi] = val;
        }
    }
}

// ---------------------------------------------------------------------------
// gemm_qkv3: A bf16, NC=768; epilogue packs qB (scaled), kB, vB (transposed).
// ---------------------------------------------------------------------------
__global__ __launch_bounds__(256) void gemm_qkv3(
    const __bf16* __restrict__ A, const __bf16* __restrict__ Wt,
    __bf16* __restrict__ qB, __bf16* __restrict__ kB, __bf16* __restrict__ vB)
{
    __shared__ __bf16 As[64*40];
    __shared__ __bf16 Bs[64*40];
    int r0 = blockIdx.x*64, c0 = blockIdx.y*64;
    int tid = threadIdx.x;
    int wv = tid >> 6, lane = tid & 63, quad = lane >> 4, mn = lane & 15;
    int sr = tid >> 2, sc = (tid & 3) * 8;
    int ga = r0 + sr; if (ga >= M_) ga = M_ - 1;

    f32x4 acc[4];
    #pragma unroll
    for (int ct = 0; ct < 4; ++ct)
        #pragma unroll
        for (int rr = 0; rr < 4; ++rr) acc[ct][rr] = 0.f;

    for (int kc = 0; kc < 8; ++kc) {
        __syncthreads();
        *(bf16x8*)&As[sr*40 + sc] =
            *(const bf16x8*)&A[(size_t)ga*256 + kc*32 + sc];
        *(bf16x8*)&Bs[sr*40 + sc] =
            *(const bf16x8*)&Wt[(size_t)(c0+sr)*256 + kc*32 + sc];
        __syncthreads();

        bf16x8 a = *(const bf16x8*)&As[(wv*16 + mn)*40 + quad*8];
        #pragma unroll
        for (int ct = 0; ct < 4; ++ct) {
            bf16x8 b = *(const bf16x8*)&Bs[(ct*16 + mn)*40 + quad*8];
            acc[ct] = __builtin_amdgcn_mfma_f32_16x16x32_bf16(a, b, acc[ct], 0, 0, 0);
        }
    }

    const float scale = 0.17677669529663687f;   // 1/sqrt(32)
    #pragma unroll
    for (int ct = 0; ct < 4; ++ct) {
        int col = c0 + ct*16 + mn;
        #pragma unroll
        for (int rr = 0; rr < 4; ++rr) {
            int row = r0 + wv*16 + quad*4 + rr;
            if (row >= M_) continue;
            int b = row / N_, n = row - b*N_;
            float val = acc[ct][rr];
            if (col < 256) {
                int h = col >> 5, dd = col & 31;
                qB[((size_t)(b*NH_+h)*NPAD + n)*32 + dd] = (__bf16)(val*scale);
            } else if (col < 512) {
                int h = (col-256) >> 5, dd = col & 31;
                kB[((size_t)(b*NH_+h)*NPAD + n)*32 + dd] = (__bf16)val;
            } else {
                int h = (col-512) >> 5, dd = col & 31;
                vB[((size_t)(b*NH_+h)*32 + dd)*NPAD + n] = (__bf16)val;
            }
        }
    }
}

// ---------------------------------------------------------------------------
// attn6: MFMA flash attention, no-max softmax, l via ones-column.
// LDS strides now 16B-aligned + <=2-way banked: lk 40, lvt/lp 80.
// Output bf16 (feeds proj GEMM staging directly).
// ---------------------------------------------------------------------------
__global__ __launch_bounds__(256) void attn6(
    const __bf16* __restrict__ qB, const __bf16* __restrict__ kB,
    const __bf16* __restrict__ vB, __bf16* __restrict__ o)
{
    int bh = blockIdx.x, b = bh >> 3, h = bh & 7;
    int q0 = blockIdx.y * 64;
    int tid = threadIdx.x;
    int wv = tid >> 6, lane = tid & 63, quad = lane >> 4, mn = lane & 15;

    __shared__ __align__(16) __bf16 lk[64*40];       // [key][d], stride 40
    __shared__ __align__(16) __bf16 lvt[48*80];      // [d][key], stride 80; row32=ones, 33..47=0
    __shared__ __align__(16) __bf16 lp[4][16*80];    // per-wave P [q][key], stride 80

    for (int e = tid; e < 16*80; e += 256)
        lvt[32*80 + e] = (e < 80) ? (__bf16)1.0f : (__bf16)0.0f;

    bf16x8 qfrag = *(const bf16x8*)(
        qB + ((size_t)bh*NPAD + q0 + wv*16 + mn)*32 + quad*8);

    f32x4 oacc0, oacc1, oacc2;
    #pragma unroll
    for (int rr = 0; rr < 4; ++rr) { oacc0[rr]=0.f; oacc1[rr]=0.f; oacc2[rr]=0.f; }

    const __bf16* kbase = kB + (size_t)bh*NPAD*32;
    const __bf16* vbase = vB + (size_t)bh*32*NPAD;
    int sr = tid >> 2, sc8 = (tid & 3) * 8;          // K staging: 64 rows x 4 chunks
    int vr = tid >> 3, vc8 = (tid & 7) * 8;          // V^T staging: 32 rows x 8 chunks

    for (int t = 0; t < 28; ++t) {
        int k0 = t*64;
        __syncthreads();
        *(bf16x8*)&lk[sr*40 + sc8] =
            *(const bf16x8*)(kbase + (size_t)(k0 + sr)*32 + sc8);
        *(bf16x8*)&lvt[vr*80 + vc8] =
            *(const bf16x8*)(vbase + (size_t)vr*NPAD + k0 + vc8);
        __syncthreads();

        // S = Q K^T
        f32x4 s[4];
        #pragma unroll
        for (int ct = 0; ct < 4; ++ct) {
            bf16x8 kf = *(const bf16x8*)&lk[(ct*16 + mn)*40 + quad*8];
            f32x4 z;
            #pragma unroll
            for (int rr = 0; rr < 4; ++rr) z[rr] = 0.f;
            s[ct] = __builtin_amdgcn_mfma_f32_16x16x32_bf16(qfrag, kf, z, 0, 0, 0);
        }

        // P = exp(S), masked; per-wave LDS round-trip (C/D -> A-frag)
        #pragma unroll
        for (int ct = 0; ct < 4; ++ct) {
            bool valid = (k0 + ct*16 + mn) < N_;
            #pragma unroll
            for (int rr = 0; rr < 4; ++rr) {
                float p = valid ? __expf(s[ct][rr]) : 0.f;
                lp[wv][(quad*4+rr)*80 + ct*16 + mn] = (__bf16)p;
            }
        }

        // O += P V  (+ l via ones-tile)
        #pragma unroll
        for (int kh = 0; kh < 2; ++kh) {
            bf16x8 pf = *(const bf16x8*)&lp[wv][mn*80 + kh*32 + quad*8];
            bf16x8 v0 = *(const bf16x8*)&lvt[ mn      *80 + kh*32 + quad*8];
            bf16x8 v1 = *(const bf16x8*)&lvt[(mn+16)*80 + kh*32 + quad*8];
            bf16x8 v2 = *(const bf16x8*)&lvt[(mn+32)*80 + kh*32 + quad*8];
            oacc0 = __builtin_amdgcn_mfma_f32_16x16x32_bf16(pf, v0, oacc0, 0, 0, 0);
            oacc1 = __builtin_amdgcn_mfma_f32_16x16x32_bf16(pf, v1, oacc1, 0, 0, 0);
            oacc2 = __builtin_amdgcn_mfma_f32_16x16x32_bf16(pf, v2, oacc2, 0, 0, 0);
        }
    }

    #pragma unroll
    for (int rr = 0; rr < 4; ++rr) {
        float l = __shfl(oacc2[rr], lane & 48);   // ones-col (d=32), mn==0 lane of quad
        int q = q0 + wv*16 + quad*4 + rr;
        if (q >= N_) continue;
        float inv = 1.0f / l;
        size_t base = ((size_t)(b*N_ + q))*C_ + h*HD_;
        o[base + mn]      = (__bf16)(oacc0[rr]*inv);
        o[base + 16 + mn] = (__bf16)(oacc1[rr]*inv);
    }
}

// ---------------------------------------------------------------------------
// feat3: LDS 32x32 tile transpose (fp32). grid (54, 8, 4).
// ---------------------------------------------------------------------------
__global__ __launch_bounds__(256) void feat3(
    const float* __restrict__ y, float* __restrict__ outf)
{
    __shared__ float tl[32][33];
    int p0 = blockIdx.x*32, c0 = blockIdx.y*32, b = blockIdx.z;
    int cc = threadIdx.x & 31, rr = threadIdx.x >> 5;
    for (int i = rr; i < 32; i += 8)
        tl[i][cc] = y[((size_t)(b*N_) + 1 + p0 + i)*C_ + c0 + cc];
    __syncthreads();
    for (int i = rr; i < 32; i += 8)
        outf[((size_t)(b*C_) + c0 + i)*P_ + p0 + cc] = tl[cc][i];
}

// ---------------------------------------------------------------------------
extern "C" void kernel_launch(void* const* d_in, const int* in_sizes, int n_in,
                              void* d_out, int out_size, void* d_ws, size_t ws_size,
                              hipStream_t stream)
{
    const float* x        = (const float*)d_in[0];
    const float* W_pe     = (const float*)d_in[1];
    const float* b_pe     = (const float*)d_in[2];
    const float* cls_tok  = (const float*)d_in[3];
    const float* ln1_g    = (const float*)d_in[4];
    const float* ln1_b    = (const float*)d_in[5];
    const float* Wqkv     = (const float*)d_in[6];
    const float* Wproj    = (const float*)d_in[7];
    const float* bproj    = (const float*)d_in[8];
    const float* ln2_g    = (const float*)d_in[9];
    const float* ln2_b    = (const float*)d_in[10];
    const float* W1       = (const float*)d_in[11];
    const float* b1       = (const float*)d_in[12];
    const float* W2       = (const float*)d_in[13];
    const float* b2       = (const float*)d_in[14];
    const float* normf_g  = (const float*)d_in[15];
    const float* normf_b  = (const float*)d_in[16];

    const size_t MC = (size_t)M_*C_;    // 1,770,496
    float*  ws  = (float*)d_ws;
    float*  t   = ws;                               // MC fp32
    float*  yf  = ws + MC;                          // MC fp32 (final ln out)
    __bf16* ybf = (__bf16*)(ws + 2*MC);             // MC bf16
    __bf16* hbf = (__bf16*)(ws + 2*MC + MC/2);      // MC bf16
    __bf16* obf = (__bf16*)(ws + 2*MC + MC);        // MC bf16
    __bf16* wT  = (__bf16*)(ws + 2*MC + 3*(MC/2));  // 786432 bf16
    __bf16* qB  = wT + 2*768*256 + 6*256*256;       // [32][NPAD][32]
    __bf16* kB  = qB + (size_t)B_*NH_*NPAD*32;
    __bf16* vB  = kB + (size_t)B_*NH_*NPAD*32;      // [32][32][NPAD]

    __bf16* projT = wT + 2*768*256;
    __bf16* w1T   = projT + 2*256*256;
    __bf16* w2T   = w1T   + 2*256*256;

    float* out_cls  = (float*)d_out;
    float* out_feat = out_cls + B_*C_;

    wprep2<<<dim3(24, 8, 8), 256, 0, stream>>>(Wqkv, Wproj, W1, W2, wT);
    embed2<<<(B_*N_*C_)/256, 256, 0, stream>>>(x, W_pe, b_pe, cls_tok, t);

    const int GRID_M = (M_ + 63) / 64;   // 109
    for (int i = 0; i < 2; ++i) {
        ln4<<<M_/4, 256, 0, stream>>>(t, ybf, ln1_g + i*C_, ln1_b + i*C_);
        gemm_qkv3<<<dim3(GRID_M, 12), 256, 0, stream>>>(
            ybf, wT + (size_t)i*768*256, qB, kB, vB);
        attn6<<<dim3(32, 28), 256, 0, stream>>>(qB, kB, vB, obf);
        gemm3<256,true,false,true,false><<<dim3(GRID_M, 4), 256, 0, stream>>>(
            obf, projT + (size_t)i*65536, bproj + i*C_, t, nullptr);
        ln4<<<M_/4, 256, 0, stream>>>(t, ybf, ln2_g + i*C_, ln2_b + i*C_);
        gemm3<256,false,true,true,true><<<dim3(GRID_M, 4), 256, 0, stream>>>(
            ybf, w1T + (size_t)i*65536, b1 + i*C_, nullptr, hbf);
        gemm3<256,true,false,true,false><<<dim3(GRID_M, 4), 256, 0, stream>>>(
            hbf, w2T + (size_t)i*65536, b2 + i*C_, t, nullptr);
    }

    ln4f<<<M_/4, 256, 0, stream>>>(t, yf, normf_g, normf_b, out_cls);
    feat3<<<dim3(54, 8, 4), 256, 0, stream>>>(yf, out_feat);
}

// Round 12
// 318.596 us; speedup vs baseline: 16.1222x; 1.0132x over previous
//
#include <hip/hip_runtime.h>
#include <hip/hip_bf16.h>
#include <math.h>

#define B_   4
#define CIN  64
#define P_   1728
#define N_   1729
#define C_   256
#define NH_  8
#define HD_  32
#define M_   (B_*N_)   // 6916 rows
#define NPAD 1792      // 28 * 64

typedef __bf16 bf16x8 __attribute__((ext_vector_type(8)));
typedef __bf16 bf16x4 __attribute__((ext_vector_type(4)));
typedef float  f32x4  __attribute__((ext_vector_type(4)));

// ---------------------------------------------------------------------------
// Patch embed. One thread per (b, n, c). Writes t fp32.
// ---------------------------------------------------------------------------
__global__ __launch_bounds__(256) void embed2(
    const float* __restrict__ x, const float* __restrict__ Wpe,
    const float* __restrict__ bpe, const float* __restrict__ cls,
    float* __restrict__ t)
{
    int idx = blockIdx.x*256 + threadIdx.x;        // [0, B*N*C)
    int c   = idx & 255;
    int n   = (idx >> 8) % N_;
    int b   = idx / (N_*256);
    if (n == 0) { t[idx] = cls[c]; return; }
    int p = n - 1;
    float acc = bpe[c];
    for (int ci = 0; ci < CIN; ++ci)
        acc += x[(size_t)(b*CIN + ci)*P_ + p] * Wpe[ci*C_ + c];
    t[idx] = acc;
}

// ---------------------------------------------------------------------------
// ln4: LayerNorm, 4 rows/block (one wave each), float4 in, bf16x4 out.
// ---------------------------------------------------------------------------
__global__ __launch_bounds__(256) void ln4(
    const float* __restrict__ in, __bf16* __restrict__ out,
    const float* __restrict__ g, const float* __restrict__ bb)
{
    int wv = threadIdx.x >> 6, lane = threadIdx.x & 63;
    size_t row = (size_t)blockIdx.x*4 + wv;
    float4 v = *(const float4*)&in[row*C_ + lane*4];
    float s1 = (v.x+v.y)+(v.z+v.w);
    float s2 = (v.x*v.x+v.y*v.y)+(v.z*v.z+v.w*v.w);
    #pragma unroll
    for (int off = 32; off >= 1; off >>= 1) {
        s1 += __shfl_xor(s1, off);
        s2 += __shfl_xor(s2, off);
    }
    float mean = s1*(1.0f/C_);
    float var  = fmaxf(s2*(1.0f/C_) - mean*mean, 0.0f);
    float rstd = rsqrtf(var + 1e-5f);
    float4 gg = *(const float4*)&g[lane*4];
    float4 bv = *(const float4*)&bb[lane*4];
    bf16x4 r;
    r[0] = (__bf16)((v.x-mean)*rstd*gg.x + bv.x);
    r[1] = (__bf16)((v.y-mean)*rstd*gg.y + bv.y);
    r[2] = (__bf16)((v.z-mean)*rstd*gg.z + bv.z);
    r[3] = (__bf16)((v.w-mean)*rstd*gg.w + bv.w);
    *(bf16x4*)&out[row*C_ + lane*4] = r;
}

// ln4f: final norm — fp32 out + cls extraction.
__global__ __launch_bounds__(256) void ln4f(
    const float* __restrict__ in, float* __restrict__ out,
    const float* __restrict__ g, const float* __restrict__ bb,
    float* __restrict__ cls_out)
{
    int wv = threadIdx.x >> 6, lane = threadIdx.x & 63;
    size_t row = (size_t)blockIdx.x*4 + wv;
    float4 v = *(const float4*)&in[row*C_ + lane*4];
    float s1 = (v.x+v.y)+(v.z+v.w);
    float s2 = (v.x*v.x+v.y*v.y)+(v.z*v.z+v.w*v.w);
    #pragma unroll
    for (int off = 32; off >= 1; off >>= 1) {
        s1 += __shfl_xor(s1, off);
        s2 += __shfl_xor(s2, off);
    }
    float mean = s1*(1.0f/C_);
    float var  = fmaxf(s2*(1.0f/C_) - mean*mean, 0.0f);
    float rstd = rsqrtf(var + 1e-5f);
    float4 gg = *(const float4*)&g[lane*4];
    float4 bv = *(const float4*)&bb[lane*4];
    float4 r;
    r.x = (v.x-mean)*rstd*gg.x + bv.x;
    r.y = (v.y-mean)*rstd*gg.y + bv.y;
    r.z = (v.z-mean)*rstd*gg.z + bv.z;
    r.w = (v.w-mean)*rstd*gg.w + bv.w;
    *(float4*)&out[row*C_ + lane*4] = r;
    if ((row % N_) == 0)
        *(float4*)&cls_out[(row / N_)*C_ + lane*4] = r;
}

// ---------------------------------------------------------------------------
// wprep2: all 8 weight matrices -> bf16 W^T[n][k] in one launch.
// ---------------------------------------------------------------------------
__global__ __launch_bounds__(256) void wprep2(
    const float* __restrict__ Wqkv, const float* __restrict__ Wproj,
    const float* __restrict__ W1,   const float* __restrict__ W2,
    __bf16* __restrict__ wT)
{
    int z = blockIdx.z, which = z >> 1, layer = z & 1;
    const float* src; __bf16* dst; int NC;
    if (which == 0) {
        src = Wqkv + (size_t)layer*C_*768;
        dst = wT   + (size_t)layer*768*256;
        NC  = 768;
    } else {
        NC = 256;
        const float* b3 = (which == 1) ? Wproj : (which == 2) ? W1 : W2;
        src = b3 + (size_t)layer*65536;
        dst = wT + 2*768*256 + (size_t)((which-1)*2 + layer)*65536;
    }
    int n0 = blockIdx.x*32; if (n0 >= NC) return;
    int k0 = blockIdx.y*32;
    __shared__ float tile[32][33];
    int c = threadIdx.x & 31, r = threadIdx.x >> 5;
    for (int rr = r; rr < 32; rr += 8)
        tile[rr][c] = src[(size_t)(k0+rr)*NC + n0 + c];
    __syncthreads();
    for (int rr = r; rr < 32; rr += 8)
        dst[(size_t)(n0+rr)*256 + k0 + c] = (__bf16)tile[c][rr];
}

// ---------------------------------------------------------------------------
// gemm3: out[M,NC] (+)= A[M,256](bf16) @ WtT (+bias fp32)(gelu). 64x64 tile,
// BK=32, XOR-swizzled dense LDS (stride 32, chunk c stored at c^(row&3)):
// 16B-aligned AND conflict-free on staging writes + fragment reads.
// ---------------------------------------------------------------------------
template<int NC, bool ADD, bool GELU, bool BIAS, bool OUTBF>
__global__ __launch_bounds__(256) void gemm3(
    const __bf16* __restrict__ A, const __bf16* __restrict__ Wt,
    const float* __restrict__ bias, float* __restrict__ outF,
    __bf16* __restrict__ outB)
{
    __shared__ __align__(16) __bf16 As[64*32];
    __shared__ __align__(16) __bf16 Bs[64*32];
    int r0 = blockIdx.x*64, c0 = blockIdx.y*64;
    int tid = threadIdx.x;
    int wv = tid >> 6, lane = tid & 63, quad = lane >> 4, mn = lane & 15;
    int sr = tid >> 2, sc = tid & 3;   // staging: row, chunk (8 bf16)
    int ga = r0 + sr; if (ga >= M_) ga = M_ - 1;   // clamp (epilogue guards)

    f32x4 acc[4];
    #pragma unroll
    for (int ct = 0; ct < 4; ++ct)
        #pragma unroll
        for (int rr = 0; rr < 4; ++rr) acc[ct][rr] = 0.f;

    for (int kc = 0; kc < 8; ++kc) {
        __syncthreads();
        *(bf16x8*)&As[sr*32 + ((sc ^ (sr & 3))*8)] =
            *(const bf16x8*)&A[(size_t)ga*256 + kc*32 + sc*8];
        *(bf16x8*)&Bs[sr*32 + ((sc ^ (sr & 3))*8)] =
            *(const bf16x8*)&Wt[(size_t)(c0+sr)*256 + kc*32 + sc*8];
        __syncthreads();

        bf16x8 a = *(const bf16x8*)&As[(wv*16 + mn)*32 + ((quad ^ (mn & 3))*8)];
        #pragma unroll
        for (int ct = 0; ct < 4; ++ct) {
            bf16x8 b = *(const bf16x8*)&Bs[(ct*16 + mn)*32 + ((quad ^ (mn & 3))*8)];
            acc[ct] = __builtin_amdgcn_mfma_f32_16x16x32_bf16(a, b, acc[ct], 0, 0, 0);
        }
    }

    #pragma unroll
    for (int ct = 0; ct < 4; ++ct) {
        int col = c0 + ct*16 + mn;
        #pragma unroll
        for (int rr = 0; rr < 4; ++rr) {
            int row = r0 + wv*16 + quad*4 + rr;
            if (row >= M_) continue;
            float val = acc[ct][rr];
            if (BIAS) val += bias[col];
            if (GELU) val = 0.5f*val*(1.f + erff(val*0.70710678118654752f));
            size_t oi = (size_t)row*NC + col;
            if (OUTBF) outB[oi] = (__bf16)val;
            else if (ADD) outF[oi] += val;
            else outF[oi] = val;
        }
    }
}

// ---------------------------------------------------------------------------
// gemm_qkv3: A bf16, NC=768; epilogue packs qB (scaled), kB, vB (transposed).
// Same swizzled LDS as gemm3.
// ---------------------------------------------------------------------------
__global__ __launch_bounds__(256) void gemm_qkv3(
    const __bf16* __restrict__ A, const __bf16* __restrict__ Wt,
    __bf16* __restrict__ qB, __bf16* __restrict__ kB, __bf16* __restrict__ vB)
{
    __shared__ __align__(16) __bf16 As[64*32];
    __shared__ __align__(16) __bf16 Bs[64*32];
    int r0 = blockIdx.x*64, c0 = blockIdx.y*64;
    int tid = threadIdx.x;
    int wv = tid >> 6, lane = tid & 63, quad = lane >> 4, mn = lane & 15;
    int sr = tid >> 2, sc = tid & 3;
    int ga = r0 + sr; if (ga >= M_) ga = M_ - 1;

    f32x4 acc[4];
    #pragma unroll
    for (int ct = 0; ct < 4; ++ct)
        #pragma unroll
        for (int rr = 0; rr < 4; ++rr) acc[ct][rr] = 0.f;

    for (int kc = 0; kc < 8; ++kc) {
        __syncthreads();
        *(bf16x8*)&As[sr*32 + ((sc ^ (sr & 3))*8)] =
            *(const bf16x8*)&A[(size_t)ga*256 + kc*32 + sc*8];
        *(bf16x8*)&Bs[sr*32 + ((sc ^ (sr & 3))*8)] =
            *(const bf16x8*)&Wt[(size_t)(c0+sr)*256 + kc*32 + sc*8];
        __syncthreads();

        bf16x8 a = *(const bf16x8*)&As[(wv*16 + mn)*32 + ((quad ^ (mn & 3))*8)];
        #pragma unroll
        for (int ct = 0; ct < 4; ++ct) {
            bf16x8 b = *(const bf16x8*)&Bs[(ct*16 + mn)*32 + ((quad ^ (mn & 3))*8)];
            acc[ct] = __builtin_amdgcn_mfma_f32_16x16x32_bf16(a, b, acc[ct], 0, 0, 0);
        }
    }

    const float scale = 0.17677669529663687f;   // 1/sqrt(32)
    #pragma unroll
    for (int ct = 0; ct < 4; ++ct) {
        int col = c0 + ct*16 + mn;
        #pragma unroll
        for (int rr = 0; rr < 4; ++rr) {
            int row = r0 + wv*16 + quad*4 + rr;
            if (row >= M_) continue;
            int b = row / N_, n = row - b*N_;
            float val = acc[ct][rr];
            if (col < 256) {
                int h = col >> 5, dd = col & 31;
                qB[((size_t)(b*NH_+h)*NPAD + n)*32 + dd] = (__bf16)(val*scale);
            } else if (col < 512) {
                int h = (col-256) >> 5, dd = col & 31;
                kB[((size_t)(b*NH_+h)*NPAD + n)*32 + dd] = (__bf16)val;
            } else {
                int h = (col-512) >> 5, dd = col & 31;
                vB[((size_t)(b*NH_+h)*32 + dd)*NPAD + n] = (__bf16)val;
            }
        }
    }
}

// ---------------------------------------------------------------------------
// attn8: MFMA flash attention, no-max softmax, l via register ones-B-frag.
// XOR-swizzled dense LDS for K (64x32) and V^T (32x64): conflict-free +
// 16B-aligned. lp stride 72 (reads conflict-free; b16 writes ~4-way).
// ---------------------------------------------------------------------------
__global__ __launch_bounds__(256) void attn8(
    const __bf16* __restrict__ qB, const __bf16* __restrict__ kB,
    const __bf16* __restrict__ vB, __bf16* __restrict__ o)
{
    int bh = blockIdx.x, b = bh >> 3, h = bh & 7;
    int q0 = blockIdx.y * 64;
    int tid = threadIdx.x;
    int wv = tid >> 6, lane = tid & 63, quad = lane >> 4, mn = lane & 15;

    __shared__ __align__(16) __bf16 lk[64*32];     // [key][d] swizzled
    __shared__ __align__(16) __bf16 lvt[32*64];    // [d][key] swizzled
    __shared__ __align__(16) __bf16 lp[4][16*72];  // per-wave P, stride 72

    bf16x8 qfrag = *(const bf16x8*)(
        qB + ((size_t)bh*NPAD + q0 + wv*16 + mn)*32 + quad*8);

    // B-frag for l accumulation: V^T rows 32..47 = [ones; zeros] -> register
    bf16x8 vones;
    #pragma unroll
    for (int j = 0; j < 8; ++j) vones[j] = (mn == 0) ? (__bf16)1.0f : (__bf16)0.0f;

    f32x4 oacc0, oacc1, oacc2;
    #pragma unroll
    for (int rr = 0; rr < 4; ++rr) { oacc0[rr]=0.f; oacc1[rr]=0.f; oacc2[rr]=0.f; }

    const __bf16* kbase = kB + (size_t)bh*NPAD*32;
    const __bf16* vbase = vB + (size_t)bh*32*NPAD;
    int sr = tid >> 2, sc = tid & 3;     // K staging: 64 rows x 4 chunks
    int vr = tid >> 3, vc = tid & 7;     // V^T staging: 32 rows x 8 chunks

    for (int t = 0; t < 28; ++t) {
        int k0 = t*64;
        __syncthreads();
        *(bf16x8*)&lk[sr*32 + ((sc ^ (sr & 3))*8)] =
            *(const bf16x8*)(kbase + (size_t)(k0 + sr)*32 + sc*8);
        *(bf16x8*)&lvt[vr*64 + ((vc ^ (vr & 7))*8)] =
            *(const bf16x8*)(vbase + (size_t)vr*NPAD + k0 + vc*8);
        __syncthreads();

        // S = Q K^T
        f32x4 s[4];
        #pragma unroll
        for (int ct = 0; ct < 4; ++ct) {
            bf16x8 kf = *(const bf16x8*)&lk[(ct*16 + mn)*32 + ((quad ^ (mn & 3))*8)];
            f32x4 z;
            #pragma unroll
            for (int rr = 0; rr < 4; ++rr) z[rr] = 0.f;
            s[ct] = __builtin_amdgcn_mfma_f32_16x16x32_bf16(qfrag, kf, z, 0, 0, 0);
        }

        // P = exp(S), masked; per-wave LDS round-trip (C/D -> A-frag)
        #pragma unroll
        for (int ct = 0; ct < 4; ++ct) {
            bool valid = (k0 + ct*16 + mn) < N_;
            #pragma unroll
            for (int rr = 0; rr < 4; ++rr) {
                float p = valid ? __expf(s[ct][rr]) : 0.f;
                lp[wv][(quad*4+rr)*72 + ct*16 + mn] = (__bf16)p;
            }
        }

        // O += P V ; l += P @ ones (register B-frag)
        #pragma unroll
        for (int kh = 0; kh < 2; ++kh) {
            bf16x8 pf = *(const bf16x8*)&lp[wv][mn*72 + kh*32 + quad*8];
            int vsw = ((kh*4 + quad) ^ (mn & 7)) * 8;
            bf16x8 v0 = *(const bf16x8*)&lvt[ mn      *64 + vsw];
            bf16x8 v1 = *(const bf16x8*)&lvt[(mn+16)*64 + vsw];
            oacc0 = __builtin_amdgcn_mfma_f32_16x16x32_bf16(pf, v0, oacc0, 0, 0, 0);
            oacc1 = __builtin_amdgcn_mfma_f32_16x16x32_bf16(pf, v1, oacc1, 0, 0, 0);
            oacc2 = __builtin_amdgcn_mfma_f32_16x16x32_bf16(pf, vones, oacc2, 0, 0, 0);
        }
    }

    #pragma unroll
    for (int rr = 0; rr < 4; ++rr) {
        float l = __shfl(oacc2[rr], lane & 48);   // col 32 -> mn==0 lane of quad
        int q = q0 + wv*16 + quad*4 + rr;
        if (q >= N_) continue;
        float inv = 1.0f / l;
        size_t base = ((size_t)(b*N_ + q))*C_ + h*HD_;
        o[base + mn]      = (__bf16)(oacc0[rr]*inv);
        o[base + 16 + mn] = (__bf16)(oacc1[rr]*inv);
    }
}

// ---------------------------------------------------------------------------
// feat3: LDS 32x32 tile transpose (fp32). grid (54, 8, 4).
// ---------------------------------------------------------------------------
__global__ __launch_bounds__(256) void feat3(
    const float* __restrict__ y, float* __restrict__ outf)
{
    __shared__ float tl[32][33];
    int p0 = blockIdx.x*32, c0 = blockIdx.y*32, b = blockIdx.z;
    int cc = threadIdx.x & 31, rr = threadIdx.x >> 5;
    for (int i = rr; i < 32; i += 8)
        tl[i][cc] = y[((size_t)(b*N_) + 1 + p0 + i)*C_ + c0 + cc];
    __syncthreads();
    for (int i = rr; i < 32; i += 8)
        outf[((size_t)(b*C_) + c0 + i)*P_ + p0 + cc] = tl[cc][i];
}

// ---------------------------------------------------------------------------
extern "C" void kernel_launch(void* const* d_in, const int* in_sizes, int n_in,
                              void* d_out, int out_size, void* d_ws, size_t ws_size,
                              hipStream_t stream)
{
    const float* x        = (const float*)d_in[0];
    const float* W_pe     = (const float*)d_in[1];
    const float* b_pe     = (const float*)d_in[2];
    const float* cls_tok  = (const float*)d_in[3];
    const float* ln1_g    = (const float*)d_in[4];
    const float* ln1_b    = (const float*)d_in[5];
    const float* Wqkv     = (const float*)d_in[6];
    const float* Wproj    = (const float*)d_in[7];
    const float* bproj    = (const float*)d_in[8];
    const float* ln2_g    = (const float*)d_in[9];
    const float* ln2_b    = (const float*)d_in[10];
    const float* W1       = (const float*)d_in[11];
    const float* b1       = (const float*)d_in[12];
    const float* W2       = (const float*)d_in[13];
    const float* b2       = (const float*)d_in[14];
    const float* normf_g  = (const float*)d_in[15];
    const float* normf_b  = (const float*)d_in[16];

    const size_t MC = (size_t)M_*C_;    // 1,770,496
    float*  ws  = (float*)d_ws;
    float*  t   = ws;                               // MC fp32
    float*  yf  = ws + MC;                          // MC fp32 (final ln out)
    __bf16* ybf = (__bf16*)(ws + 2*MC);             // MC bf16
    __bf16* hbf = (__bf16*)(ws + 2*MC + MC/2);      // MC bf16
    __bf16* obf = (__bf16*)(ws + 2*MC + MC);        // MC bf16
    __bf16* wT  = (__bf16*)(ws + 2*MC + 3*(MC/2));  // 786432 bf16
    __bf16* qB  = wT + 2*768*256 + 6*256*256;       // [32][NPAD][32]
    __bf16* kB  = qB + (size_t)B_*NH_*NPAD*32;
    __bf16* vB  = kB + (size_t)B_*NH_*NPAD*32;      // [32][32][NPAD]

    __bf16* projT = wT + 2*768*256;
    __bf16* w1T   = projT + 2*256*256;
    __bf16* w2T   = w1T   + 2*256*256;

    float* out_cls  = (float*)d_out;
    float* out_feat = out_cls + B_*C_;

    wprep2<<<dim3(24, 8, 8), 256, 0, stream>>>(Wqkv, Wproj, W1, W2, wT);
    embed2<<<(B_*N_*C_)/256, 256, 0, stream>>>(x, W_pe, b_pe, cls_tok, t);

    const int GRID_M = (M_ + 63) / 64;   // 109
    for (int i = 0; i < 2; ++i) {
        ln4<<<M_/4, 256, 0, stream>>>(t, ybf, ln1_g + i*C_, ln1_b + i*C_);
        gemm_qkv3<<<dim3(GRID_M, 12), 256, 0, stream>>>(
            ybf, wT + (size_t)i*768*256, qB, kB, vB);
        attn8<<<dim3(32, 28), 256, 0, stream>>>(qB, kB, vB, obf);
        gemm3<256,true,false,true,false><<<dim3(GRID_M, 4), 256, 0, stream>>>(
            obf, projT + (size_t)i*65536, bproj + i*C_, t, nullptr);
        ln4<<<M_/4, 256, 0, stream>>>(t, ybf, ln2_g + i*C_, ln2_b + i*C_);
        gemm3<256,false,true,true,true><<<dim3(GRID_M, 4), 256, 0, stream>>>(
            ybf, w1T + (size_t)i*65536, b1 + i*C_, nullptr, hbf);
        gemm3<256,true,false,true,false><<<dim3(GRID_M, 4), 256, 0, stream>>>(
            hbf, w2T + (size_t)i*65536, b2 + i*C_, t, nullptr);
    }

    ln4f<<<M_/4, 256, 0, stream>>>(t, yf, normf_g, normf_b, out_cls);
    feat3<<<dim3(54, 8, 4), 256, 0, stream>>>(yf, out_feat);
}